// Round 10
// baseline (1279.894 us; speedup 1.0000x reference)
//
#include <hip/hip_runtime.h>
#include <stdint.h>

typedef unsigned char u8;
typedef unsigned short us;
typedef unsigned int u32;

#define CDIM  128
#define KNBR  48
#define HEADS 8
#define DHEAD 16
#define FFDIM 256

using bf16x8 = __attribute__((ext_vector_type(8))) short;  // 8 bf16 (4 VGPRs)
using f32x4  = __attribute__((ext_vector_type(4))) float;  // 4 fp32

__device__ inline float blo32(u32 u) { union { u32 i; float f; } v; v.i = u << 16; return v.f; }
__device__ inline float bhi32(u32 u) { union { u32 i; float f; } v; v.i = u & 0xFFFF0000u; return v.f; }
__device__ inline float bf2f(us u) { union { u32 i; float f; } v; v.i = ((u32)u) << 16; return v.f; }
__device__ inline us f2bf(float x) {
    union { float f; u32 i; } v; v.f = x;
    u32 r = v.i + 0x7FFFu + ((v.i >> 16) & 1u);
    return (us)(r >> 16);
}
// HW packed f32x2 -> bf16x2 (RNE), one instruction (gfx950; no builtin).
__device__ inline u32 cvtpk(float a, float b) {
    u32 r;
    asm("v_cvt_pk_bf16_f32 %0, %1, %2" : "=v"(r) : "v"(a), "v"(b));
    return r;
}

// ---------------------------------------------------------------------------
// K0: probe key_mask storage (int32 vs u8 bool). flag=1 -> u8 storage.
// ---------------------------------------------------------------------------
__global__ void k_mask_probe(const u32* __restrict__ mw, int nwords,
                             int* __restrict__ flag)
{
    u32 any = 0;
    for (int j = blockIdx.x * blockDim.x + threadIdx.x; j < nwords;
         j += gridDim.x * blockDim.x)
        any |= mw[j] & 0xFFFFFF00u;
    if (any) atomicOr(flag, 1);
}

// ---------------------------------------------------------------------------
// K1: QKV projection, 2-D register tiling (8 rows x 4 cols per thread).
// Block: 384 thr = 96 col-groups x 4 row-groups; 32 rows x 384 cols.
// Q f32; Fk/Fv emitted bf16.
// ---------------------------------------------------------------------------
__global__ __launch_bounds__(384) void k_qkv(
    const float* __restrict__ F, const float* __restrict__ W,
    const float* __restrict__ B,
    float* __restrict__ Q, us* __restrict__ FkB, us* __restrict__ FvB, int N)
{
    __shared__ float xL[32 * CDIM];
    int row0 = blockIdx.x * 32;
    int t = threadIdx.x;
    {
        const float4* F4 = (const float4*)F;
        float4* xL4 = (float4*)xL;
        for (int o = t; o < 32 * 32; o += 384) {
            int r = o >> 5, c4 = o & 31;
            int row = row0 + r;
            xL4[o] = (row < N) ? F4[(size_t)row * 32 + c4]
                               : make_float4(0.f, 0.f, 0.f, 0.f);
        }
    }
    __syncthreads();

    int cg = t % 96, rg = t / 96;          // cols cg*4..+3, rows rg*8..+7
    int e0 = cg * 4;
    const float4* Wp = (const float4*)W;
    float acc[8][4];
    #pragma unroll
    for (int r = 0; r < 8; ++r)
        #pragma unroll
        for (int j = 0; j < 4; ++j) acc[r][j] = 0.f;

    #pragma unroll 4
    for (int c4 = 0; c4 < 32; ++c4) {
        float4 w0 = Wp[(e0 + 0) * 32 + c4];
        float4 w1 = Wp[(e0 + 1) * 32 + c4];
        float4 w2 = Wp[(e0 + 2) * 32 + c4];
        float4 w3 = Wp[(e0 + 3) * 32 + c4];
        #pragma unroll
        for (int r = 0; r < 8; ++r) {
            float4 xv = *(const float4*)&xL[(rg * 8 + r) * CDIM + c4 * 4];
            acc[r][0] += xv.x*w0.x + xv.y*w0.y + xv.z*w0.z + xv.w*w0.w;
            acc[r][1] += xv.x*w1.x + xv.y*w1.y + xv.z*w1.z + xv.w*w1.w;
            acc[r][2] += xv.x*w2.x + xv.y*w2.y + xv.z*w2.z + xv.w*w2.w;
            acc[r][3] += xv.x*w3.x + xv.y*w3.y + xv.z*w3.z + xv.w*w3.w;
        }
    }
    float4 bv = *(const float4*)&B[e0];
    #pragma unroll
    for (int r = 0; r < 8; ++r) {
        int row = row0 + rg * 8 + r;
        if (row >= N) continue;
        float a0 = acc[r][0] + bv.x, a1 = acc[r][1] + bv.y;
        float a2 = acc[r][2] + bv.z, a3 = acc[r][3] + bv.w;
        if (e0 < 128) {
            *(float4*)&Q[(size_t)row * CDIM + e0] = make_float4(a0, a1, a2, a3);
        } else if (e0 < 256) {
            uint2 pk; pk.x = cvtpk(a0, a1); pk.y = cvtpk(a2, a3);
            *(uint2*)&FkB[(size_t)row * CDIM + (e0 - 128)] = pk;
        } else {
            uint2 pk; pk.x = cvtpk(a0, a1); pk.y = cvtpk(a2, a3);
            *(uint2*)&FvB[(size_t)row * CDIM + (e0 - 256)] = pk;
        }
    }
}

// ---------------------------------------------------------------------------
// K2: attention (R9-verbatim; best measured: 703 us, no spill).
// ---------------------------------------------------------------------------
__global__ __launch_bounds__(256, 4) void k_attn(
    const float* __restrict__ coords, const int* __restrict__ kidx,
    const u8* __restrict__ kmask_u8, const int* __restrict__ kmask_i32,
    const int* __restrict__ maskflag,
    const float* __restrict__ Q, const us* __restrict__ FkB,
    const us* __restrict__ FvB,
    const float* __restrict__ wk, const float* __restrict__ wv,
    const float* __restrict__ kpw, const float* __restrict__ kpb,
    float* __restrict__ CTX)
{
    __shared__ __align__(16) u8 SM[14656];
    us*    qwH   = (us*)(SM);
    us*    qwL   = (us*)(SM + 2176);
    float* scL   = (float*)(SM + 4352);
    float* Ql    = (float*)(SM + 6016);
    float* rel   = (float*)(SM + 6528);
    float* kpw0S = (float*)(SM + 7104);
    float* kpw1S = (float*)(SM + 7616);
    float* kpw2S = (float*)(SM + 8128);
    float* kpbS  = (float*)(SM + 8640);
    int*   idxl  = (int*)  (SM + 9152);
    u8*    mskl  = (u8*)   (SM + 9344);
    float* Pb    = (float*)(SM + 9408);
    float* pc    = (float*)(SM + 13632);

    int n = blockIdx.x;
    int t = threadIdx.x;
    int w = t >> 6, lane = t & 63;

    if (t < KNBR) {
        int idx = kidx[n * KNBR + t];
        idxl[t] = idx;
        mskl[t] = maskflag[0] ? kmask_u8[n * KNBR + t]
                              : (u8)kmask_i32[n * KNBR + t];
        rel[t * 3 + 0] = coords[idx * 3 + 0] - coords[n * 3 + 0];
        rel[t * 3 + 1] = coords[idx * 3 + 1] - coords[n * 3 + 1];
        rel[t * 3 + 2] = coords[idx * 3 + 2] - coords[n * 3 + 2];
    }
    if (t < 128) {
        kpw0S[t] = kpw[t * 3 + 0];
        kpw1S[t] = kpw[t * 3 + 1];
        kpw2S[t] = kpw[t * 3 + 2];
        kpbS[t]  = kpb[t];
    } else {
        Ql[t - 128] = Q[n * CDIM + (t - 128)];
    }
    __syncthreads();

    {
        int h = t >> 5, c4 = t & 31;
        const float* qh = Ql + h * DHEAD;
        float a0=0.f, a1=0.f, a2=0.f, a3=0.f;
        #pragma unroll
        for (int d = 0; d < DHEAD; ++d) {
            float q = qh[d];
            float4 wr = *(const float4*)(wk + (size_t)(h * DHEAD + d) * CDIM + c4 * 4);
            a0 += q * wr.x; a1 += q * wr.y; a2 += q * wr.z; a3 += q * wr.w;
        }
        uint2 ph, pl;
        ph.x = cvtpk(a0, a1);
        ph.y = cvtpk(a2, a3);
        pl.x = cvtpk(a0 - blo32(ph.x), a1 - bhi32(ph.x));
        pl.y = cvtpk(a2 - blo32(ph.y), a3 - bhi32(ph.y));
        *(uint2*)&qwH[h * 136 + c4 * 4] = ph;
        *(uint2*)&qwL[h * 136 + c4 * 4] = pl;
    }

    union U8 { bf16x8 v; u32 wd[4]; };
    U8 BH[4], BL[4];
    if (w < 3) {
        int kk = w * 16 + (lane & 15);
        int cb0 = (lane >> 4) * 8;
        float r0 = rel[kk * 3], r1 = rel[kk * 3 + 1], r2 = rel[kk * 3 + 2];
        #pragma unroll
        for (int s = 0; s < 4; ++s) {
            int cb = cb0 + s * 32;
            float4 x0 = *(const float4*)&kpw0S[cb], x1 = *(const float4*)&kpw0S[cb + 4];
            float4 y0 = *(const float4*)&kpw1S[cb], y1 = *(const float4*)&kpw1S[cb + 4];
            float4 z0 = *(const float4*)&kpw2S[cb], z1 = *(const float4*)&kpw2S[cb + 4];
            float4 b0 = *(const float4*)&kpbS[cb],  b1 = *(const float4*)&kpbS[cb + 4];
            float p[8];
            p[0] = fmaxf(b0.x + r0*x0.x + r1*y0.x + r2*z0.x, 0.f);
            p[1] = fmaxf(b0.y + r0*x0.y + r1*y0.y + r2*z0.y, 0.f);
            p[2] = fmaxf(b0.z + r0*x0.z + r1*y0.z + r2*z0.z, 0.f);
            p[3] = fmaxf(b0.w + r0*x0.w + r1*y0.w + r2*z0.w, 0.f);
            p[4] = fmaxf(b1.x + r0*x1.x + r1*y1.x + r2*z1.x, 0.f);
            p[5] = fmaxf(b1.y + r0*x1.y + r1*y1.y + r2*z1.y, 0.f);
            p[6] = fmaxf(b1.z + r0*x1.z + r1*y1.z + r2*z1.z, 0.f);
            p[7] = fmaxf(b1.w + r0*x1.w + r1*y1.w + r2*z1.w, 0.f);
            #pragma unroll
            for (int j = 0; j < 4; ++j) {
                u32 hh = cvtpk(p[2*j], p[2*j+1]);
                BH[s].wd[j] = hh;
                BL[s].wd[j] = cvtpk(p[2*j] - blo32(hh), p[2*j+1] - bhi32(hh));
            }
        }
    } else {
        #pragma unroll
        for (int i = 0; i < 6; ++i) {
            int o = lane * 6 + i;
            int k = o >> 3, h = o & 7;
            const float* qh = Ql + h * DHEAD;
            const uint4* fk = (const uint4*)(FkB + (size_t)idxl[k] * CDIM + h * DHEAD);
            uint4 fa = fk[0], fb = fk[1];
            float s = qh[0]*blo32(fa.x) + qh[1]*bhi32(fa.x)
                    + qh[2]*blo32(fa.y) + qh[3]*bhi32(fa.y)
                    + qh[4]*blo32(fa.z) + qh[5]*bhi32(fa.z)
                    + qh[6]*blo32(fa.w) + qh[7]*bhi32(fa.w)
                    + qh[8]*blo32(fb.x) + qh[9]*bhi32(fb.x)
                    + qh[10]*blo32(fb.y) + qh[11]*bhi32(fb.y)
                    + qh[12]*blo32(fb.z) + qh[13]*bhi32(fb.z)
                    + qh[14]*blo32(fb.w) + qh[15]*bhi32(fb.w);
            scL[h * 52 + k] = s;
        }
    }
    __syncthreads();

    if (w < 3) {
        f32x4 acc = {0.f, 0.f, 0.f, 0.f};
        int arow = lane & 15;
        int ko = (lane >> 4) * 8;
        bool aval = arow < 8;
        bf16x8 zz = {0,0,0,0,0,0,0,0};
        #pragma unroll
        for (int s = 0; s < 4; ++s) {
            int c0 = s * 32 + ko;
            bf16x8 ah = aval ? *(const bf16x8*)(qwH + arow * 136 + c0) : zz;
            bf16x8 al = aval ? *(const bf16x8*)(qwL + arow * 136 + c0) : zz;
            acc = __builtin_amdgcn_mfma_f32_16x16x32_bf16(ah, BH[s].v, acc, 0, 0, 0);
            acc = __builtin_amdgcn_mfma_f32_16x16x32_bf16(ah, BL[s].v, acc, 0, 0, 0);
            acc = __builtin_amdgcn_mfma_f32_16x16x32_bf16(al, BH[s].v, acc, 0, 0, 0);
        }
        if (lane < 32) {
            int kk = w * 16 + (lane & 15);
            int rb = (lane >> 4) * 4;
            u8 mk = mskl[kk];
            #pragma unroll
            for (int j = 0; j < 4; ++j) {
                int h = rb + j;
                float s = acc[j] + scL[h * 52 + kk];
                scL[h * 52 + kk] = mk ? -1e30f : s * 0.25f;
            }
        }
    }
    __syncthreads();

    {
        int h = t >> 5, l32 = t & 31;
        float* sc = scL + h * 52;
        float v0 = sc[l32];
        float v1 = (l32 < KNBR - 32) ? sc[l32 + 32] : -1e30f;
        float m = fmaxf(v0, v1);
        #pragma unroll
        for (int off = 16; off >= 1; off >>= 1)
            m = fmaxf(m, __shfl_xor(m, off, 32));
        float e0 = __expf(v0 - m);
        float e1 = (l32 < KNBR - 32) ? __expf(v1 - m) : 0.f;
        float s = e0 + e1;
        #pragma unroll
        for (int off = 16; off >= 1; off >>= 1)
            s += __shfl_xor(s, off, 32);
        float inv = 1.f / s;
        sc[l32] = e0 * inv;
        if (l32 < KNBR - 32) sc[l32 + 32] = e1 * inv;
    }
    __syncthreads();

    {
        bf16x8 AH[2], AL[2];
        int arow = lane & 15;
        bool av = arow < 8;
        #pragma unroll
        for (int st = 0; st < 2; ++st) {
            int k0 = (lane >> 4) * 8 + st * 32;
            float pr[8];
            if (av && k0 < KNBR) {
                float4 s0 = *(const float4*)&scL[arow * 52 + k0];
                float4 s1 = *(const float4*)&scL[arow * 52 + k0 + 4];
                pr[0]=s0.x; pr[1]=s0.y; pr[2]=s0.z; pr[3]=s0.w;
                pr[4]=s1.x; pr[5]=s1.y; pr[6]=s1.z; pr[7]=s1.w;
            } else {
                #pragma unroll
                for (int j = 0; j < 8; ++j) pr[j] = 0.f;
            }
            U8 ah, al;
            #pragma unroll
            for (int j = 0; j < 4; ++j) {
                u32 hh = cvtpk(pr[2*j], pr[2*j+1]);
                ah.wd[j] = hh;
                al.wd[j] = cvtpk(pr[2*j] - blo32(hh), pr[2*j+1] - bhi32(hh));
            }
            AH[st] = ah.v; AL[st] = al.v;
        }
        #pragma unroll
        for (int ct = 0; ct < 2; ++ct) {
            int c = w * 32 + ct * 16 + (lane & 15);
            float w0 = kpw0S[c], w1 = kpw1S[c], w2 = kpw2S[c], bb = kpbS[c];
            f32x4 acc = {0.f, 0.f, 0.f, 0.f};
            #pragma unroll
            for (int st = 0; st < 2; ++st) {
                int k0 = (lane >> 4) * 8 + st * 32;
                U8 bh;
                if (k0 < KNBR) {
                    #pragma unroll
                    for (int j = 0; j < 4; ++j) {
                        const float* ra = rel + (k0 + 2*j) * 3;
                        const float* rb = rel + (k0 + 2*j + 1) * 3;
                        float pa = fmaxf(bb + ra[0]*w0 + ra[1]*w1 + ra[2]*w2, 0.f);
                        float pb = fmaxf(bb + rb[0]*w0 + rb[1]*w1 + rb[2]*w2, 0.f);
                        bh.wd[j] = cvtpk(pa, pb);
                    }
                } else {
                    bh.wd[0]=bh.wd[1]=bh.wd[2]=bh.wd[3]=0u;
                }
                acc = __builtin_amdgcn_mfma_f32_16x16x32_bf16(AH[st], bh.v, acc, 0, 0, 0);
                acc = __builtin_amdgcn_mfma_f32_16x16x32_bf16(AL[st], bh.v, acc, 0, 0, 0);
            }
            if (lane < 32) {
                int rb2 = (lane >> 4) * 4;
                #pragma unroll
                for (int j = 0; j < 4; ++j)
                    Pb[(rb2 + j) * 132 + c] = acc[j];
            }
        }
    }
    __syncthreads();

    {
        int c = t & 127, half = t >> 7;
        int h = c >> 4;
        const float* sc = scL + h * 52;
        float accF = 0.f;
        #pragma unroll 4
        for (int kk = 0; kk < 24; ++kk) {
            int k = half * 24 + kk;
            accF += sc[k] * bf2f(FvB[(size_t)idxl[k] * CDIM + c]);
        }
        const float4* wr = (const float4*)(wv + (size_t)c * CDIM) + half * 16;
        const float4* pb4 = (const float4*)(Pb + h * 132) + half * 16;
        #pragma unroll 4
        for (int j = 0; j < 16; ++j) {
            float4 wq = wr[j], p = pb4[j];
            accF += wq.x*p.x + wq.y*p.y + wq.z*p.z + wq.w*p.w;
        }
        pc[half * 128 + c] = accF;
    }
    __syncthreads();
    if (t < CDIM) CTX[n * CDIM + t] = pc[t] + pc[128 + t];
}

// ---------------------------------------------------------------------------
// K3/K6: 128->128 GEMM + bias (+res) + LN (+relu), 2-D register tiling.
// Block 256 thr = 32 col-groups x 8 row-groups; 64 rows. aL reuses xL.
// ---------------------------------------------------------------------------
__global__ __launch_bounds__(256) void k_proj_ln(
    const float* __restrict__ X, const float* __restrict__ RES,
    const float* __restrict__ W, const float* __restrict__ B,
    const float* __restrict__ G, const float* __restrict__ LB,
    float* __restrict__ OUT, int N, int relu_out)
{
    __shared__ float xL[64 * CDIM];       // 32 KB; reused as aL
    __shared__ float mu[64], rs[64];
    int row0 = blockIdx.x * 64;
    int t = threadIdx.x;
    {
        const float4* X4 = (const float4*)X;
        float4* xL4 = (float4*)xL;
        #pragma unroll
        for (int o = t; o < 64 * 32; o += 256) {
            int r = o >> 5, c4 = o & 31;
            int row = row0 + r;
            xL4[o] = (row < N) ? X4[(size_t)row * 32 + c4]
                               : make_float4(0.f, 0.f, 0.f, 0.f);
        }
    }
    __syncthreads();

    int cg = t & 31, rg = t >> 5;          // cols cg*4..+3, rows rg*8..+7
    int e0 = cg * 4;
    const float4* Wp = (const float4*)W;
    float acc[8][4];
    #pragma unroll
    for (int r = 0; r < 8; ++r)
        #pragma unroll
        for (int j = 0; j < 4; ++j) acc[r][j] = 0.f;

    #pragma unroll 4
    for (int c4 = 0; c4 < 32; ++c4) {
        float4 w0 = Wp[(e0 + 0) * 32 + c4];
        float4 w1 = Wp[(e0 + 1) * 32 + c4];
        float4 w2 = Wp[(e0 + 2) * 32 + c4];
        float4 w3 = Wp[(e0 + 3) * 32 + c4];
        #pragma unroll
        for (int r = 0; r < 8; ++r) {
            float4 xv = *(const float4*)&xL[(rg * 8 + r) * CDIM + c4 * 4];
            acc[r][0] += xv.x*w0.x + xv.y*w0.y + xv.z*w0.z + xv.w*w0.w;
            acc[r][1] += xv.x*w1.x + xv.y*w1.y + xv.z*w1.z + xv.w*w1.w;
            acc[r][2] += xv.x*w2.x + xv.y*w2.y + xv.z*w2.z + xv.w*w2.w;
            acc[r][3] += xv.x*w3.x + xv.y*w3.y + xv.z*w3.z + xv.w*w3.w;
        }
    }
    float4 bv = *(const float4*)&B[e0];
    float4 av[8];
    #pragma unroll
    for (int r = 0; r < 8; ++r) {
        int row = row0 + rg * 8 + r;
        av[r] = make_float4(acc[r][0] + bv.x, acc[r][1] + bv.y,
                            acc[r][2] + bv.z, acc[r][3] + bv.w);
        if (RES != nullptr && row < N) {
            float4 rv = *(const float4*)&RES[(size_t)row * CDIM + e0];
            av[r].x += rv.x; av[r].y += rv.y; av[r].z += rv.z; av[r].w += rv.w;
        }
    }
    __syncthreads();                       // xL reads done -> safe to overwrite
    #pragma unroll
    for (int r = 0; r < 8; ++r)
        *(float4*)&xL[(rg * 8 + r) * CDIM + e0] = av[r];
    __syncthreads();

    {   // LN stats: 4 threads per row, 32 elems each
        int r = t >> 2, j = t & 3;
        const float4* a4 = (const float4*)&xL[r * CDIM + j * 32];
        float s = 0.f;
        #pragma unroll
        for (int q = 0; q < 8; ++q) {
            float4 v = a4[q];
            s += v.x + v.y + v.z + v.w;
        }
        s += __shfl_xor(s, 2, 4);
        s += __shfl_xor(s, 1, 4);
        float mean = s * (1.f / 128.f);
        float var = 0.f;
        #pragma unroll
        for (int q = 0; q < 8; ++q) {
            float4 v = a4[q];
            float d0 = v.x - mean, d1 = v.y - mean, d2 = v.z - mean, d3 = v.w - mean;
            var += d0*d0 + d1*d1 + d2*d2 + d3*d3;
        }
        var += __shfl_xor(var, 2, 4);
        var += __shfl_xor(var, 1, 4);
        if (j == 0) { mu[r] = mean; rs[r] = rsqrtf(var * (1.f / 128.f) + 1e-5f); }
    }
    __syncthreads();

    {
        float4* OUT4 = (float4*)OUT;
        #pragma unroll
        for (int o = t; o < 64 * 32; o += 256) {
            int r = o >> 5, c4 = o & 31;
            int row = row0 + r;
            if (row < N) {
                float4 v = *(const float4*)&xL[r * CDIM + c4 * 4];
                float4 g = *(const float4*)&G[c4 * 4];
                float4 lb = *(const float4*)&LB[c4 * 4];
                float m = mu[r], ir = rs[r];
                float4 y;
                y.x = (v.x - m) * ir * g.x + lb.x;
                y.y = (v.y - m) * ir * g.y + lb.y;
                y.z = (v.z - m) * ir * g.z + lb.z;
                y.w = (v.w - m) * ir * g.w + lb.w;
                if (relu_out) {
                    y.x = fmaxf(y.x, 0.f); y.y = fmaxf(y.y, 0.f);
                    y.z = fmaxf(y.z, 0.f); y.w = fmaxf(y.w, 0.f);
                }
                OUT4[(size_t)row * 32 + c4] = y;
            }
        }
    }
}

// ---------------------------------------------------------------------------
// K4: ff1 = relu(x @ W1^T + b1), 128 -> 256. 2-D tiling: 256 thr =
// 64 col-groups x 4 row-groups; 32 rows x 256 cols.
// ---------------------------------------------------------------------------
__global__ __launch_bounds__(256) void k_ff1(
    const float* __restrict__ X, const float* __restrict__ W,
    const float* __restrict__ B, float* __restrict__ HID, int N)
{
    __shared__ float xL[32 * CDIM];       // 16 KB
    int row0 = blockIdx.x * 32;
    int t = threadIdx.x;
    {
        const float4* X4 = (const float4*)X;
        float4* xL4 = (float4*)xL;
        #pragma unroll
        for (int o = t; o < 32 * 32; o += 256) {
            int r = o >> 5, c4 = o & 31;
            int row = row0 + r;
            xL4[o] = (row < N) ? X4[(size_t)row * 32 + c4]
                               : make_float4(0.f, 0.f, 0.f, 0.f);
        }
    }
    __syncthreads();

    int cg = t & 63, rg = t >> 6;          // cols cg*4..+3 (256), rows rg*8..+7
    int e0 = cg * 4;
    const float4* Wp = (const float4*)W;
    float acc[8][4];
    #pragma unroll
    for (int r = 0; r < 8; ++r)
        #pragma unroll
        for (int j = 0; j < 4; ++j) acc[r][j] = 0.f;

    #pragma unroll 4
    for (int c4 = 0; c4 < 32; ++c4) {
        float4 w0 = Wp[(e0 + 0) * 32 + c4];
        float4 w1 = Wp[(e0 + 1) * 32 + c4];
        float4 w2 = Wp[(e0 + 2) * 32 + c4];
        float4 w3 = Wp[(e0 + 3) * 32 + c4];
        #pragma unroll
        for (int r = 0; r < 8; ++r) {
            float4 xv = *(const float4*)&xL[(rg * 8 + r) * CDIM + c4 * 4];
            acc[r][0] += xv.x*w0.x + xv.y*w0.y + xv.z*w0.z + xv.w*w0.w;
            acc[r][1] += xv.x*w1.x + xv.y*w1.y + xv.z*w1.z + xv.w*w1.w;
            acc[r][2] += xv.x*w2.x + xv.y*w2.y + xv.z*w2.z + xv.w*w2.w;
            acc[r][3] += xv.x*w3.x + xv.y*w3.y + xv.z*w3.z + xv.w*w3.w;
        }
    }
    float4 bv = *(const float4*)&B[e0];
    #pragma unroll
    for (int r = 0; r < 8; ++r) {
        int row = row0 + rg * 8 + r;
        if (row < N) {
            float4 y;
            y.x = fmaxf(acc[r][0] + bv.x, 0.f);
            y.y = fmaxf(acc[r][1] + bv.y, 0.f);
            y.z = fmaxf(acc[r][2] + bv.z, 0.f);
            y.w = fmaxf(acc[r][3] + bv.w, 0.f);
            *(float4*)&HID[(size_t)row * FFDIM + e0] = y;
        }
    }
}

// ---------------------------------------------------------------------------
// K5: x2 = LN(x1 + hid @ W2^T + b2), 256 -> 128. 2-D tiling: 256 thr =
// 32 col-groups x 8 row-groups(4 rows each); 32 rows. aL reuses xL.
// ---------------------------------------------------------------------------
__global__ __launch_bounds__(256) void k_ff2_ln(
    const float* __restrict__ HID, const float* __restrict__ RES,
    const float* __restrict__ W, const float* __restrict__ B,
    const float* __restrict__ G, const float* __restrict__ LB,
    float* __restrict__ OUT, int N)
{
    __shared__ float xL[32 * FFDIM];      // 32 KB; aL reuses (stride 256)
    __shared__ float mu[32], rs[32];
    int row0 = blockIdx.x * 32;
    int t = threadIdx.x;
    {
        const float4* H4 = (const float4*)HID;
        float4* xL4 = (float4*)xL;
        #pragma unroll
        for (int o = t; o < 32 * 64; o += 256) {
            int r = o >> 6, c4 = o & 63;
            int row = row0 + r;
            xL4[o] = (row < N) ? H4[(size_t)row * 64 + c4]
                               : make_float4(0.f, 0.f, 0.f, 0.f);
        }
    }
    __syncthreads();

    int cg = t & 31, rg = t >> 5;          // cols cg*4..+3, rows rg*4..+3
    int e0 = cg * 4;
    const float4* Wp = (const float4*)W;
    float acc[4][4];
    #pragma unroll
    for (int r = 0; r < 4; ++r)
        #pragma unroll
        for (int j = 0; j < 4; ++j) acc[r][j] = 0.f;

    #pragma unroll 4
    for (int c4 = 0; c4 < 64; ++c4) {
        float4 w0 = Wp[(e0 + 0) * 64 + c4];
        float4 w1 = Wp[(e0 + 1) * 64 + c4];
        float4 w2 = Wp[(e0 + 2) * 64 + c4];
        float4 w3 = Wp[(e0 + 3) * 64 + c4];
        #pragma unroll
        for (int r = 0; r < 4; ++r) {
            float4 xv = *(const float4*)&xL[(rg * 4 + r) * FFDIM + c4 * 4];
            acc[r][0] += xv.x*w0.x + xv.y*w0.y + xv.z*w0.z + xv.w*w0.w;
            acc[r][1] += xv.x*w1.x + xv.y*w1.y + xv.z*w1.z + xv.w*w1.w;
            acc[r][2] += xv.x*w2.x + xv.y*w2.y + xv.z*w2.z + xv.w*w2.w;
            acc[r][3] += xv.x*w3.x + xv.y*w3.y + xv.z*w3.z + xv.w*w3.w;
        }
    }
    float4 bv = *(const float4*)&B[e0];
    float4 av[4];
    #pragma unroll
    for (int r = 0; r < 4; ++r) {
        int row = row0 + rg * 4 + r;
        av[r] = make_float4(acc[r][0] + bv.x, acc[r][1] + bv.y,
                            acc[r][2] + bv.z, acc[r][3] + bv.w);
        if (row < N) {
            float4 rv = *(const float4*)&RES[(size_t)row * CDIM + e0];
            av[r].x += rv.x; av[r].y += rv.y; av[r].z += rv.z; av[r].w += rv.w;
        }
    }
    __syncthreads();
    #pragma unroll
    for (int r = 0; r < 4; ++r)
        *(float4*)&xL[(rg * 4 + r) * FFDIM + e0] = av[r];
    __syncthreads();

    {   // LN stats: 8 threads per row, 16 elems each
        int r = t >> 3, j = t & 7;
        const float4* a4 = (const float4*)&xL[r * FFDIM + j * 16];
        float s = 0.f;
        #pragma unroll
        for (int q = 0; q < 4; ++q) {
            float4 v = a4[q];
            s += v.x + v.y + v.z + v.w;
        }
        s += __shfl_xor(s, 4, 8);
        s += __shfl_xor(s, 2, 8);
        s += __shfl_xor(s, 1, 8);
        float mean = s * (1.f / 128.f);
        float var = 0.f;
        #pragma unroll
        for (int q = 0; q < 4; ++q) {
            float4 v = a4[q];
            float d0 = v.x - mean, d1 = v.y - mean, d2 = v.z - mean, d3 = v.w - mean;
            var += d0*d0 + d1*d1 + d2*d2 + d3*d3;
        }
        var += __shfl_xor(var, 4, 8);
        var += __shfl_xor(var, 2, 8);
        var += __shfl_xor(var, 1, 8);
        if (j == 0) { mu[r] = mean; rs[r] = rsqrtf(var * (1.f / 128.f) + 1e-5f); }
    }
    __syncthreads();

    {
        float4* OUT4 = (float4*)OUT;
        #pragma unroll
        for (int o = t; o < 32 * 32; o += 256) {
            int r = o >> 5, c4 = o & 31;
            int row = row0 + r;
            if (row < N) {
                float4 v = *(const float4*)&xL[r * FFDIM + c4 * 4];
                float4 g = *(const float4*)&G[c4 * 4];
                float4 lb = *(const float4*)&LB[c4 * 4];
                float m = mu[r], ir = rs[r];
                float4 y;
                y.x = (v.x - m) * ir * g.x + lb.x;
                y.y = (v.y - m) * ir * g.y + lb.y;
                y.z = (v.z - m) * ir * g.z + lb.z;
                y.w = (v.w - m) * ir * g.w + lb.w;
                OUT4[(size_t)row * 32 + c4] = y;
            }
        }
    }
}

// ---------------------------------------------------------------------------
extern "C" void kernel_launch(void* const* d_in, const int* in_sizes, int n_in,
                              void* d_out, int out_size, void* d_ws, size_t ws_size,
                              hipStream_t stream)
{
    const float* F      = (const float*)d_in[0];
    const float* coords = (const float*)d_in[1];
    const int*   kidx   = (const int*)d_in[2];
    const void*  kmask  = d_in[3];
    const float* ipw    = (const float*)d_in[4];
    const float* ipb    = (const float*)d_in[5];
    const float* opw    = (const float*)d_in[6];
    const float* opb    = (const float*)d_in[7];
    const float* kpw    = (const float*)d_in[8];
    const float* kpb    = (const float*)d_in[9];
    const float* ln1g   = (const float*)d_in[10];
    const float* ln1b   = (const float*)d_in[11];
    const float* ln2g   = (const float*)d_in[12];
    const float* ln2b   = (const float*)d_in[13];
    const float* w1     = (const float*)d_in[14];
    const float* b1     = (const float*)d_in[15];
    const float* w2     = (const float*)d_in[16];
    const float* b2     = (const float*)d_in[17];
    const float* ow     = (const float*)d_in[18];
    const float* ob     = (const float*)d_in[19];
    const float* ln3g   = (const float*)d_in[20];
    const float* ln3b   = (const float*)d_in[21];

    int N = in_sizes[0] / CDIM;
    size_t NC = (size_t)N * CDIM;

    float* ws  = (float*)d_ws;
    float* Q    = ws;
    us*    FkB  = (us*)(ws + NC);
    us*    FvB  = (us*)(ws + NC) + NC;
    float* CTX  = ws + 2 * NC;
    float* X1   = Q;
    float* HID  = ws + NC;
    float* X2   = ws + 3 * NC;
    int*   mflag = (int*)(ws + 4 * NC);

    const float* wk = ipw + CDIM * CDIM;
    const float* wv = ipw + 2 * CDIM * CDIM;

    hipMemsetAsync(mflag, 0, sizeof(int), stream);
    int nwords = (N * KNBR) / 4;
    k_mask_probe<<<256, 256, 0, stream>>>((const u32*)kmask, nwords, mflag);

    k_qkv<<<(N + 31) / 32, 384, 0, stream>>>(F, ipw, ipb, Q, FkB, FvB, N);
    k_attn<<<N, 256, 0, stream>>>(coords, kidx, (const u8*)kmask,
                                  (const int*)kmask, mflag, Q, FkB, FvB,
                                  wk, wv, kpw, kpb, CTX);
    k_proj_ln<<<(N + 63) / 64, 256, 0, stream>>>(CTX, F, opw, opb,
                                                 ln1g, ln1b, X1, N, 0);
    k_ff1<<<(N + 31) / 32, 256, 0, stream>>>(X1, w1, b1, HID, N);
    k_ff2_ln<<<(N + 31) / 32, 256, 0, stream>>>(HID, X1, w2, b2,
                                                ln2g, ln2b, X2, N);
    k_proj_ln<<<(N + 63) / 64, 256, 0, stream>>>(X2, nullptr, ow, ob,
                                                 ln3g, ln3b, (float*)d_out, N, 1);
}

// Round 11
// 1035.786 us; speedup vs baseline: 1.2357x; 1.2357x over previous
//
#include <hip/hip_runtime.h>
#include <stdint.h>

typedef unsigned char u8;
typedef unsigned short us;
typedef unsigned int u32;

#define CDIM  128
#define KNBR  48
#define HEADS 8
#define DHEAD 16
#define FFDIM 256

using bf16x8 = __attribute__((ext_vector_type(8))) short;  // 8 bf16 (4 VGPRs)
using f32x4  = __attribute__((ext_vector_type(4))) float;  // 4 fp32

__device__ inline float blo32(u32 u) { union { u32 i; float f; } v; v.i = u << 16; return v.f; }
__device__ inline float bhi32(u32 u) { union { u32 i; float f; } v; v.i = u & 0xFFFF0000u; return v.f; }
__device__ inline float bf2f(us u) { union { u32 i; float f; } v; v.i = ((u32)u) << 16; return v.f; }
__device__ inline us f2bf(float x) {
    union { float f; u32 i; } v; v.f = x;
    u32 r = v.i + 0x7FFFu + ((v.i >> 16) & 1u);
    return (us)(r >> 16);
}
// HW packed f32x2 -> bf16x2 (RNE), one instruction (gfx950; no builtin).
__device__ inline u32 cvtpk(float a, float b) {
    u32 r;
    asm("v_cvt_pk_bf16_f32 %0, %1, %2" : "=v"(r) : "v"(a), "v"(b));
    return r;
}

// ---------------------------------------------------------------------------
// K0: probe key_mask storage (int32 vs u8 bool). flag=1 -> u8 storage.
// ---------------------------------------------------------------------------
__global__ void k_mask_probe(const u32* __restrict__ mw, int nwords,
                             int* __restrict__ flag)
{
    u32 any = 0;
    for (int j = blockIdx.x * blockDim.x + threadIdx.x; j < nwords;
         j += gridDim.x * blockDim.x)
        any |= mw[j] & 0xFFFFFF00u;
    if (any) atomicOr(flag, 1);
}

// ---------------------------------------------------------------------------
// K0b: weight transpose to WT4[c4][e] (float4 blocks). One-time, ~590 KB.
// Makes the GEMM inner-loop W load coalesced: lane e reads WT4[c4*E+e].
// ---------------------------------------------------------------------------
__global__ __launch_bounds__(256) void k_wt(
    const float* __restrict__ W, float* __restrict__ WT, int E, int C4)
{
    int i = blockIdx.x * 256 + threadIdx.x;    // over E*C4
    if (i < E * C4) {
        int e = i / C4, c4 = i - e * C4;
        float4 v = *(const float4*)(W + (size_t)e * (C4 * 4) + c4 * 4);
        ((float4*)WT)[(size_t)c4 * E + e] = v;
    }
}

// ---------------------------------------------------------------------------
// K1: QKV projection (R9 structure; W loads via coalesced WT).
// Block 384 thr: thread owns col e, 8 rows. Q f32; Fk/Fv bf16.
// ---------------------------------------------------------------------------
__global__ __launch_bounds__(384) void k_qkv(
    const float* __restrict__ F, const float* __restrict__ WT,
    const float* __restrict__ B,
    float* __restrict__ Q, us* __restrict__ FkB, us* __restrict__ FvB, int N)
{
    __shared__ float xL[8][CDIM];
    int row0 = blockIdx.x * 8;
    int t = threadIdx.x;
    for (int o = t; o < 8 * CDIM; o += 384) {
        int r = o >> 7, c = o & 127;
        int row = row0 + r;
        xL[r][c] = (row < N) ? F[row * CDIM + c] : 0.f;
    }
    __syncthreads();

    int e = t;  // 0..383
    const float4* WT4 = (const float4*)WT;
    float acc[8] = {0.f,0.f,0.f,0.f,0.f,0.f,0.f,0.f};
    #pragma unroll 8
    for (int c4 = 0; c4 < CDIM / 4; ++c4) {
        float4 w = WT4[c4 * 384 + e];          // coalesced across lanes
        #pragma unroll
        for (int r = 0; r < 8; ++r) {
            const float* x = &xL[r][c4 * 4];
            acc[r] += x[0]*w.x + x[1]*w.y + x[2]*w.z + x[3]*w.w;
        }
    }
    float bv = B[e];
    if (e < 128) {
        #pragma unroll
        for (int r = 0; r < 8; ++r) {
            int row = row0 + r;
            if (row < N) Q[row * CDIM + e] = acc[r] + bv;
        }
    } else if (e < 256) {
        int eo = e - 128;
        #pragma unroll
        for (int r = 0; r < 8; ++r) {
            int row = row0 + r;
            if (row < N) FkB[(size_t)row * CDIM + eo] = f2bf(acc[r] + bv);
        }
    } else {
        int eo = e - 256;
        #pragma unroll
        for (int r = 0; r < 8; ++r) {
            int row = row0 + r;
            if (row < N) FvB[(size_t)row * CDIM + eo] = f2bf(acc[r] + bv);
        }
    }
}

// ---------------------------------------------------------------------------
// K2: attention (R9-verbatim; best measured: 703 us, no spill).
// ---------------------------------------------------------------------------
__global__ __launch_bounds__(256, 4) void k_attn(
    const float* __restrict__ coords, const int* __restrict__ kidx,
    const u8* __restrict__ kmask_u8, const int* __restrict__ kmask_i32,
    const int* __restrict__ maskflag,
    const float* __restrict__ Q, const us* __restrict__ FkB,
    const us* __restrict__ FvB,
    const float* __restrict__ wk, const float* __restrict__ wv,
    const float* __restrict__ kpw, const float* __restrict__ kpb,
    float* __restrict__ CTX)
{
    __shared__ __align__(16) u8 SM[14656];
    us*    qwH   = (us*)(SM);
    us*    qwL   = (us*)(SM + 2176);
    float* scL   = (float*)(SM + 4352);
    float* Ql    = (float*)(SM + 6016);
    float* rel   = (float*)(SM + 6528);
    float* kpw0S = (float*)(SM + 7104);
    float* kpw1S = (float*)(SM + 7616);
    float* kpw2S = (float*)(SM + 8128);
    float* kpbS  = (float*)(SM + 8640);
    int*   idxl  = (int*)  (SM + 9152);
    u8*    mskl  = (u8*)   (SM + 9344);
    float* Pb    = (float*)(SM + 9408);
    float* pc    = (float*)(SM + 13632);

    int n = blockIdx.x;
    int t = threadIdx.x;
    int w = t >> 6, lane = t & 63;

    if (t < KNBR) {
        int idx = kidx[n * KNBR + t];
        idxl[t] = idx;
        mskl[t] = maskflag[0] ? kmask_u8[n * KNBR + t]
                              : (u8)kmask_i32[n * KNBR + t];
        rel[t * 3 + 0] = coords[idx * 3 + 0] - coords[n * 3 + 0];
        rel[t * 3 + 1] = coords[idx * 3 + 1] - coords[n * 3 + 1];
        rel[t * 3 + 2] = coords[idx * 3 + 2] - coords[n * 3 + 2];
    }
    if (t < 128) {
        kpw0S[t] = kpw[t * 3 + 0];
        kpw1S[t] = kpw[t * 3 + 1];
        kpw2S[t] = kpw[t * 3 + 2];
        kpbS[t]  = kpb[t];
    } else {
        Ql[t - 128] = Q[n * CDIM + (t - 128)];
    }
    __syncthreads();

    {
        int h = t >> 5, c4 = t & 31;
        const float* qh = Ql + h * DHEAD;
        float a0=0.f, a1=0.f, a2=0.f, a3=0.f;
        #pragma unroll
        for (int d = 0; d < DHEAD; ++d) {
            float q = qh[d];
            float4 wr = *(const float4*)(wk + (size_t)(h * DHEAD + d) * CDIM + c4 * 4);
            a0 += q * wr.x; a1 += q * wr.y; a2 += q * wr.z; a3 += q * wr.w;
        }
        uint2 ph, pl;
        ph.x = cvtpk(a0, a1);
        ph.y = cvtpk(a2, a3);
        pl.x = cvtpk(a0 - blo32(ph.x), a1 - bhi32(ph.x));
        pl.y = cvtpk(a2 - blo32(ph.y), a3 - bhi32(ph.y));
        *(uint2*)&qwH[h * 136 + c4 * 4] = ph;
        *(uint2*)&qwL[h * 136 + c4 * 4] = pl;
    }

    union U8 { bf16x8 v; u32 wd[4]; };
    U8 BH[4], BL[4];
    if (w < 3) {
        int kk = w * 16 + (lane & 15);
        int cb0 = (lane >> 4) * 8;
        float r0 = rel[kk * 3], r1 = rel[kk * 3 + 1], r2 = rel[kk * 3 + 2];
        #pragma unroll
        for (int s = 0; s < 4; ++s) {
            int cb = cb0 + s * 32;
            float4 x0 = *(const float4*)&kpw0S[cb], x1 = *(const float4*)&kpw0S[cb + 4];
            float4 y0 = *(const float4*)&kpw1S[cb], y1 = *(const float4*)&kpw1S[cb + 4];
            float4 z0 = *(const float4*)&kpw2S[cb], z1 = *(const float4*)&kpw2S[cb + 4];
            float4 b0 = *(const float4*)&kpbS[cb],  b1 = *(const float4*)&kpbS[cb + 4];
            float p[8];
            p[0] = fmaxf(b0.x + r0*x0.x + r1*y0.x + r2*z0.x, 0.f);
            p[1] = fmaxf(b0.y + r0*x0.y + r1*y0.y + r2*z0.y, 0.f);
            p[2] = fmaxf(b0.z + r0*x0.z + r1*y0.z + r2*z0.z, 0.f);
            p[3] = fmaxf(b0.w + r0*x0.w + r1*y0.w + r2*z0.w, 0.f);
            p[4] = fmaxf(b1.x + r0*x1.x + r1*y1.x + r2*z1.x, 0.f);
            p[5] = fmaxf(b1.y + r0*x1.y + r1*y1.y + r2*z1.y, 0.f);
            p[6] = fmaxf(b1.z + r0*x1.z + r1*y1.z + r2*z1.z, 0.f);
            p[7] = fmaxf(b1.w + r0*x1.w + r1*y1.w + r2*z1.w, 0.f);
            #pragma unroll
            for (int j = 0; j < 4; ++j) {
                u32 hh = cvtpk(p[2*j], p[2*j+1]);
                BH[s].wd[j] = hh;
                BL[s].wd[j] = cvtpk(p[2*j] - blo32(hh), p[2*j+1] - bhi32(hh));
            }
        }
    } else {
        #pragma unroll
        for (int i = 0; i < 6; ++i) {
            int o = lane * 6 + i;
            int k = o >> 3, h = o & 7;
            const float* qh = Ql + h * DHEAD;
            const uint4* fk = (const uint4*)(FkB + (size_t)idxl[k] * CDIM + h * DHEAD);
            uint4 fa = fk[0], fb = fk[1];
            float s = qh[0]*blo32(fa.x) + qh[1]*bhi32(fa.x)
                    + qh[2]*blo32(fa.y) + qh[3]*bhi32(fa.y)
                    + qh[4]*blo32(fa.z) + qh[5]*bhi32(fa.z)
                    + qh[6]*blo32(fa.w) + qh[7]*bhi32(fa.w)
                    + qh[8]*blo32(fb.x) + qh[9]*bhi32(fb.x)
                    + qh[10]*blo32(fb.y) + qh[11]*bhi32(fb.y)
                    + qh[12]*blo32(fb.z) + qh[13]*bhi32(fb.z)
                    + qh[14]*blo32(fb.w) + qh[15]*bhi32(fb.w);
            scL[h * 52 + k] = s;
        }
    }
    __syncthreads();

    if (w < 3) {
        f32x4 acc = {0.f, 0.f, 0.f, 0.f};
        int arow = lane & 15;
        int ko = (lane >> 4) * 8;
        bool aval = arow < 8;
        bf16x8 zz = {0,0,0,0,0,0,0,0};
        #pragma unroll
        for (int s = 0; s < 4; ++s) {
            int c0 = s * 32 + ko;
            bf16x8 ah = aval ? *(const bf16x8*)(qwH + arow * 136 + c0) : zz;
            bf16x8 al = aval ? *(const bf16x8*)(qwL + arow * 136 + c0) : zz;
            acc = __builtin_amdgcn_mfma_f32_16x16x32_bf16(ah, BH[s].v, acc, 0, 0, 0);
            acc = __builtin_amdgcn_mfma_f32_16x16x32_bf16(ah, BL[s].v, acc, 0, 0, 0);
            acc = __builtin_amdgcn_mfma_f32_16x16x32_bf16(al, BH[s].v, acc, 0, 0, 0);
        }
        if (lane < 32) {
            int kk = w * 16 + (lane & 15);
            int rb = (lane >> 4) * 4;
            u8 mk = mskl[kk];
            #pragma unroll
            for (int j = 0; j < 4; ++j) {
                int h = rb + j;
                float s = acc[j] + scL[h * 52 + kk];
                scL[h * 52 + kk] = mk ? -1e30f : s * 0.25f;
            }
        }
    }
    __syncthreads();

    {
        int h = t >> 5, l32 = t & 31;
        float* sc = scL + h * 52;
        float v0 = sc[l32];
        float v1 = (l32 < KNBR - 32) ? sc[l32 + 32] : -1e30f;
        float m = fmaxf(v0, v1);
        #pragma unroll
        for (int off = 16; off >= 1; off >>= 1)
            m = fmaxf(m, __shfl_xor(m, off, 32));
        float e0 = __expf(v0 - m);
        float e1 = (l32 < KNBR - 32) ? __expf(v1 - m) : 0.f;
        float s = e0 + e1;
        #pragma unroll
        for (int off = 16; off >= 1; off >>= 1)
            s += __shfl_xor(s, off, 32);
        float inv = 1.f / s;
        sc[l32] = e0 * inv;
        if (l32 < KNBR - 32) sc[l32 + 32] = e1 * inv;
    }
    __syncthreads();

    {
        bf16x8 AH[2], AL[2];
        int arow = lane & 15;
        bool av = arow < 8;
        #pragma unroll
        for (int st = 0; st < 2; ++st) {
            int k0 = (lane >> 4) * 8 + st * 32;
            float pr[8];
            if (av && k0 < KNBR) {
                float4 s0 = *(const float4*)&scL[arow * 52 + k0];
                float4 s1 = *(const float4*)&scL[arow * 52 + k0 + 4];
                pr[0]=s0.x; pr[1]=s0.y; pr[2]=s0.z; pr[3]=s0.w;
                pr[4]=s1.x; pr[5]=s1.y; pr[6]=s1.z; pr[7]=s1.w;
            } else {
                #pragma unroll
                for (int j = 0; j < 8; ++j) pr[j] = 0.f;
            }
            U8 ah, al;
            #pragma unroll
            for (int j = 0; j < 4; ++j) {
                u32 hh = cvtpk(pr[2*j], pr[2*j+1]);
                ah.wd[j] = hh;
                al.wd[j] = cvtpk(pr[2*j] - blo32(hh), pr[2*j+1] - bhi32(hh));
            }
            AH[st] = ah.v; AL[st] = al.v;
        }
        #pragma unroll
        for (int ct = 0; ct < 2; ++ct) {
            int c = w * 32 + ct * 16 + (lane & 15);
            float w0 = kpw0S[c], w1 = kpw1S[c], w2 = kpw2S[c], bb = kpbS[c];
            f32x4 acc = {0.f, 0.f, 0.f, 0.f};
            #pragma unroll
            for (int st = 0; st < 2; ++st) {
                int k0 = (lane >> 4) * 8 + st * 32;
                U8 bh;
                if (k0 < KNBR) {
                    #pragma unroll
                    for (int j = 0; j < 4; ++j) {
                        const float* ra = rel + (k0 + 2*j) * 3;
                        const float* rb = rel + (k0 + 2*j + 1) * 3;
                        float pa = fmaxf(bb + ra[0]*w0 + ra[1]*w1 + ra[2]*w2, 0.f);
                        float pb = fmaxf(bb + rb[0]*w0 + rb[1]*w1 + rb[2]*w2, 0.f);
                        bh.wd[j] = cvtpk(pa, pb);
                    }
                } else {
                    bh.wd[0]=bh.wd[1]=bh.wd[2]=bh.wd[3]=0u;
                }
                acc = __builtin_amdgcn_mfma_f32_16x16x32_bf16(AH[st], bh.v, acc, 0, 0, 0);
                acc = __builtin_amdgcn_mfma_f32_16x16x32_bf16(AL[st], bh.v, acc, 0, 0, 0);
            }
            if (lane < 32) {
                int rb2 = (lane >> 4) * 4;
                #pragma unroll
                for (int j = 0; j < 4; ++j)
                    Pb[(rb2 + j) * 132 + c] = acc[j];
            }
        }
    }
    __syncthreads();

    {
        int c = t & 127, half = t >> 7;
        int h = c >> 4;
        const float* sc = scL + h * 52;
        float accF = 0.f;
        #pragma unroll 4
        for (int kk = 0; kk < 24; ++kk) {
            int k = half * 24 + kk;
            accF += sc[k] * bf2f(FvB[(size_t)idxl[k] * CDIM + c]);
        }
        const float4* wr = (const float4*)(wv + (size_t)c * CDIM) + half * 16;
        const float4* pb4 = (const float4*)(Pb + h * 132) + half * 16;
        #pragma unroll 4
        for (int j = 0; j < 16; ++j) {
            float4 wq = wr[j], p = pb4[j];
            accF += wq.x*p.x + wq.y*p.y + wq.z*p.z + wq.w*p.w;
        }
        pc[half * 128 + c] = accF;
    }
    __syncthreads();
    if (t < CDIM) CTX[n * CDIM + t] = pc[t] + pc[128 + t];
}

// ---------------------------------------------------------------------------
// K3/K6: 128->128 GEMM + bias (+res) + LN (+relu). R9 structure; coalesced WT.
// ---------------------------------------------------------------------------
__global__ __launch_bounds__(256) void k_proj_ln(
    const float* __restrict__ X, const float* __restrict__ RES,
    const float* __restrict__ WT, const float* __restrict__ B,
    const float* __restrict__ G, const float* __restrict__ LB,
    float* __restrict__ OUT, int N, int relu_out)
{
    __shared__ float xL[16][CDIM];
    __shared__ float aL[16][CDIM + 4];
    __shared__ float mu[16], rs[16];
    int row0 = blockIdx.x * 16;
    int t = threadIdx.x;
    for (int o = t; o < 16 * CDIM; o += 256) {
        int r = o >> 7, c = o & 127;
        int row = row0 + r;
        xL[r][c] = (row < N) ? X[row * CDIM + c] : 0.f;
    }
    __syncthreads();

    int e = t & 127, rh = t >> 7;
    const float4* WT4 = (const float4*)WT;
    float acc[8] = {0.f,0.f,0.f,0.f,0.f,0.f,0.f,0.f};
    #pragma unroll 8
    for (int c4 = 0; c4 < CDIM / 4; ++c4) {
        float4 w = WT4[c4 * 128 + e];          // coalesced across lanes
        #pragma unroll
        for (int i = 0; i < 8; ++i) {
            const float* x = &xL[rh * 8 + i][c4 * 4];
            acc[i] += x[0]*w.x + x[1]*w.y + x[2]*w.z + x[3]*w.w;
        }
    }
    float bv = B[e];
    #pragma unroll
    for (int i = 0; i < 8; ++i) {
        int r = rh * 8 + i, row = row0 + r;
        float a = acc[i] + bv;
        if (RES != nullptr && row < N) a += RES[row * CDIM + e];
        aL[r][e] = a;
    }
    __syncthreads();

    {
        int r = t >> 4, j = t & 15;
        float s = 0.f;
        #pragma unroll
        for (int jj = 0; jj < 8; ++jj) s += aL[r][j * 8 + jj];
        #pragma unroll
        for (int off = 8; off >= 1; off >>= 1) s += __shfl_xor(s, off, 16);
        float mean = s * (1.f / 128.f);
        float v = 0.f;
        #pragma unroll
        for (int jj = 0; jj < 8; ++jj) {
            float d = aL[r][j * 8 + jj] - mean; v += d * d;
        }
        #pragma unroll
        for (int off = 8; off >= 1; off >>= 1) v += __shfl_xor(v, off, 16);
        if (j == 0) { mu[r] = mean; rs[r] = rsqrtf(v * (1.f / 128.f) + 1e-5f); }
    }
    __syncthreads();

    for (int o = t; o < 16 * CDIM; o += 256) {
        int r = o >> 7, c = o & 127;
        int row = row0 + r;
        if (row < N) {
            float y = (aL[r][c] - mu[r]) * rs[r] * G[c] + LB[c];
            if (relu_out) y = fmaxf(y, 0.f);
            OUT[row * CDIM + c] = y;
        }
    }
}

// ---------------------------------------------------------------------------
// K4: ff1 = relu(x @ W1^T + b1), 128 -> 256. R9 structure; coalesced WT.
// ---------------------------------------------------------------------------
__global__ __launch_bounds__(256) void k_ff1(
    const float* __restrict__ X, const float* __restrict__ WT,
    const float* __restrict__ B, float* __restrict__ HID, int N)
{
    __shared__ float xL[8][CDIM];
    int row0 = blockIdx.x * 8;
    int t = threadIdx.x;
    for (int o = t; o < 8 * CDIM; o += 256) {
        int r = o >> 7, c = o & 127;
        int row = row0 + r;
        xL[r][c] = (row < N) ? X[row * CDIM + c] : 0.f;
    }
    __syncthreads();

    int e = t;
    const float4* WT4 = (const float4*)WT;
    float acc[8] = {0.f,0.f,0.f,0.f,0.f,0.f,0.f,0.f};
    #pragma unroll 8
    for (int c4 = 0; c4 < CDIM / 4; ++c4) {
        float4 w = WT4[c4 * 256 + e];          // coalesced across lanes
        #pragma unroll
        for (int r = 0; r < 8; ++r) {
            const float* x = &xL[r][c4 * 4];
            acc[r] += x[0]*w.x + x[1]*w.y + x[2]*w.z + x[3]*w.w;
        }
    }
    float bv = B[e];
    #pragma unroll
    for (int r = 0; r < 8; ++r) {
        int row = row0 + r;
        if (row < N) HID[row * FFDIM + e] = fmaxf(acc[r] + bv, 0.f);
    }
}

// ---------------------------------------------------------------------------
// K5: x2 = LN(x1 + hid @ W2^T + b2), 256 -> 128. R9 structure; coalesced WT.
// ---------------------------------------------------------------------------
__global__ __launch_bounds__(256) void k_ff2_ln(
    const float* __restrict__ HID, const float* __restrict__ RES,
    const float* __restrict__ WT, const float* __restrict__ B,
    const float* __restrict__ G, const float* __restrict__ LB,
    float* __restrict__ OUT, int N)
{
    __shared__ float xL[16][FFDIM];
    __shared__ float aL[16][CDIM + 4];
    __shared__ float mu[16], rs[16];
    int row0 = blockIdx.x * 16;
    int t = threadIdx.x;
    for (int o = t; o < 16 * FFDIM; o += 256) {
        int r = o >> 8, c = o & 255;
        int row = row0 + r;
        xL[r][c] = (row < N) ? HID[row * FFDIM + c] : 0.f;
    }
    __syncthreads();

    int e = t & 127, rh = t >> 7;
    const float4* WT4 = (const float4*)WT;
    float acc[8] = {0.f,0.f,0.f,0.f,0.f,0.f,0.f,0.f};
    #pragma unroll 8
    for (int c4 = 0; c4 < FFDIM / 4; ++c4) {
        float4 w = WT4[c4 * 128 + e];          // coalesced across lanes
        #pragma unroll
        for (int i = 0; i < 8; ++i) {
            const float* x = &xL[rh * 8 + i][c4 * 4];
            acc[i] += x[0]*w.x + x[1]*w.y + x[2]*w.z + x[3]*w.w;
        }
    }
    float bv = B[e];
    #pragma unroll
    for (int i = 0; i < 8; ++i) {
        int r = rh * 8 + i, row = row0 + r;
        float a = acc[i] + bv;
        if (row < N) a += RES[row * CDIM + e];
        aL[r][e] = a;
    }
    __syncthreads();

    {
        int r = t >> 4, j = t & 15;
        float s = 0.f;
        #pragma unroll
        for (int jj = 0; jj < 8; ++jj) s += aL[r][j * 8 + jj];
        #pragma unroll
        for (int off = 8; off >= 1; off >>= 1) s += __shfl_xor(s, off, 16);
        float mean = s * (1.f / 128.f);
        float v = 0.f;
        #pragma unroll
        for (int jj = 0; jj < 8; ++jj) {
            float d = aL[r][j * 8 + jj] - mean; v += d * d;
        }
        #pragma unroll
        for (int off = 8; off >= 1; off >>= 1) v += __shfl_xor(v, off, 16);
        if (j == 0) { mu[r] = mean; rs[r] = rsqrtf(v * (1.f / 128.f) + 1e-5f); }
    }
    __syncthreads();

    for (int o = t; o < 16 * CDIM; o += 256) {
        int r = o >> 7, c = o & 127;
        int row = row0 + r;
        if (row < N)
            OUT[row * CDIM + c] = (aL[r][c] - mu[r]) * rs[r] * G[c] + LB[c];
    }
}

// ---------------------------------------------------------------------------
extern "C" void kernel_launch(void* const* d_in, const int* in_sizes, int n_in,
                              void* d_out, int out_size, void* d_ws, size_t ws_size,
                              hipStream_t stream)
{
    const float* F      = (const float*)d_in[0];
    const float* coords = (const float*)d_in[1];
    const int*   kidx   = (const int*)d_in[2];
    const void*  kmask  = d_in[3];
    const float* ipw    = (const float*)d_in[4];
    const float* ipb    = (const float*)d_in[5];
    const float* opw    = (const float*)d_in[6];
    const float* opb    = (const float*)d_in[7];
    const float* kpw    = (const float*)d_in[8];
    const float* kpb    = (const float*)d_in[9];
    const float* ln1g   = (const float*)d_in[10];
    const float* ln1b   = (const float*)d_in[11];
    const float* ln2g   = (const float*)d_in[12];
    const float* ln2b   = (const float*)d_in[13];
    const float* w1     = (const float*)d_in[14];
    const float* b1     = (const float*)d_in[15];
    const float* w2     = (const float*)d_in[16];
    const float* b2     = (const float*)d_in[17];
    const float* ow     = (const float*)d_in[18];
    const float* ob     = (const float*)d_in[19];
    const float* ln3g   = (const float*)d_in[20];
    const float* ln3b   = (const float*)d_in[21];

    int N = in_sizes[0] / CDIM;
    size_t NC = (size_t)N * CDIM;

    float* ws  = (float*)d_ws;
    // layout (floats):
    //   [0,   NC)    Q  (later X1)
    //   [NC,  1.5NC) FkB (bf16)  } HID = [NC,3NC) after attention
    //   [1.5NC,2NC)  FvB (bf16)  }
    //   [2NC, 3NC)   CTX (dead after proj_ln1)
    //   [3NC, 4NC)   X2
    //   [4NC, ...)   WTq(49152) WTo(16384) WT1(32768) WT2(32768) WTw(16384) mflag
    float* Q    = ws;
    us*    FkB  = (us*)(ws + NC);
    us*    FvB  = (us*)(ws + NC) + NC;
    float* CTX  = ws + 2 * NC;
    float* X1   = Q;
    float* HID  = ws + NC;
    float* X2   = ws + 3 * NC;
    float* WTq  = ws + 4 * NC;
    float* WTo  = WTq + 384 * 128;
    float* WT1  = WTo + 128 * 128;
    float* WT2  = WT1 + 256 * 128;
    float* WTw  = WT2 + 128 * 256;
    int*   mflag = (int*)(WTw + 128 * 128);

    const float* wk = ipw + CDIM * CDIM;
    const float* wv = ipw + 2 * CDIM * CDIM;

    hipMemsetAsync(mflag, 0, sizeof(int), stream);
    int nwords = (N * KNBR) / 4;
    k_mask_probe<<<256, 256, 0, stream>>>((const u32*)kmask, nwords, mflag);

    // weight transposes (one-time, ~590 KB total)
    k_wt<<<(384 * 32 + 255) / 256, 256, 0, stream>>>(ipw, WTq, 384, 32);
    k_wt<<<(128 * 32 + 255) / 256, 256, 0, stream>>>(opw, WTo, 128, 32);
    k_wt<<<(256 * 32 + 255) / 256, 256, 0, stream>>>(w1,  WT1, 256, 32);
    k_wt<<<(128 * 64 + 255) / 256, 256, 0, stream>>>(w2,  WT2, 128, 64);
    k_wt<<<(128 * 32 + 255) / 256, 256, 0, stream>>>(ow,  WTw, 128, 32);

    k_qkv<<<(N + 7) / 8, 384, 0, stream>>>(F, WTq, ipb, Q, FkB, FvB, N);
    k_attn<<<N, 256, 0, stream>>>(coords, kidx, (const u8*)kmask,
                                  (const int*)kmask, mflag, Q, FkB, FvB,
                                  wk, wv, kpw, kpb, CTX);
    k_proj_ln<<<(N + 15) / 16, 256, 0, stream>>>(CTX, F, WTo, opb,
                                                 ln1g, ln1b, X1, N, 0);
    k_ff1<<<(N + 7) / 8, 256, 0, stream>>>(X1, WT1, b1, HID, N);
    k_ff2_ln<<<(N + 15) / 16, 256, 0, stream>>>(HID, X1, WT2, b2,
                                                ln2g, ln2b, X2, N);
    k_proj_ln<<<(N + 15) / 16, 256, 0, stream>>>(X2, nullptr, WTw, ob,
                                                 ln3g, ln3b, (float*)d_out, N, 1);
}

// Round 12
// 870.719 us; speedup vs baseline: 1.4699x; 1.1896x over previous
//
#include <hip/hip_runtime.h>
#include <stdint.h>

typedef unsigned char u8;
typedef unsigned short us;
typedef unsigned int u32;

#define CDIM  128
#define KNBR  48
#define HEADS 8
#define DHEAD 16
#define FFDIM 256

using bf16x8 = __attribute__((ext_vector_type(8))) short;  // 8 bf16 (4 VGPRs)
using f32x4  = __attribute__((ext_vector_type(4))) float;  // 4 fp32

__device__ inline float blo32(u32 u) { union { u32 i; float f; } v; v.i = u << 16; return v.f; }
__device__ inline float bhi32(u32 u) { union { u32 i; float f; } v; v.i = u & 0xFFFF0000u; return v.f; }
__device__ inline float bf2f(us u) { union { u32 i; float f; } v; v.i = ((u32)u) << 16; return v.f; }
__device__ inline us f2bf(float x) {
    union { float f; u32 i; } v; v.f = x;
    u32 r = v.i + 0x7FFFu + ((v.i >> 16) & 1u);
    return (us)(r >> 16);
}
// HW packed f32x2 -> bf16x2 (RNE), one instruction (gfx950; no builtin).
__device__ inline u32 cvtpk(float a, float b) {
    u32 r;
    asm("v_cvt_pk_bf16_f32 %0, %1, %2" : "=v"(r) : "v"(a), "v"(b));
    return r;
}

// ---------------------------------------------------------------------------
// K0: probe key_mask storage (int32 vs u8 bool). flag=1 -> u8 storage.
// ---------------------------------------------------------------------------
__global__ void k_mask_probe(const u32* __restrict__ mw, int nwords,
                             int* __restrict__ flag)
{
    u32 any = 0;
    for (int j = blockIdx.x * blockDim.x + threadIdx.x; j < nwords;
         j += gridDim.x * blockDim.x)
        any |= mw[j] & 0xFFFFFF00u;
    if (any) atomicOr(flag, 1);
}

// ---------------------------------------------------------------------------
// K0b: f32 W -> WT4[c4][e] float4-transpose (for k_qkv's coalesced loads).
// ---------------------------------------------------------------------------
__global__ __launch_bounds__(256) void k_wt(
    const float* __restrict__ W, float* __restrict__ WT, int E, int C4)
{
    int i = blockIdx.x * 256 + threadIdx.x;
    if (i < E * C4) {
        int e = i / C4, c4 = i - e * C4;
        float4 v = *(const float4*)(W + (size_t)e * (C4 * 4) + c4 * 4);
        ((float4*)WT)[(size_t)c4 * E + e] = v;
    }
}

// ---------------------------------------------------------------------------
// K0c: f32 W -> bf16 row-major (for the tail MFMA GEMMs). n = elems/2.
// ---------------------------------------------------------------------------
__global__ __launch_bounds__(256) void k_wb(
    const float* __restrict__ W, us* __restrict__ WB, int n2)
{
    int i = blockIdx.x * 256 + threadIdx.x;
    if (i < n2) {
        float2 v = *(const float2*)(W + (size_t)i * 2);
        ((u32*)WB)[i] = cvtpk(v.x, v.y);
    }
}

// ---------------------------------------------------------------------------
// K1: QKV projection (R11-verbatim; coalesced WT). Q f32; Fk/Fv bf16.
// ---------------------------------------------------------------------------
__global__ __launch_bounds__(384) void k_qkv(
    const float* __restrict__ F, const float* __restrict__ WT,
    const float* __restrict__ B,
    float* __restrict__ Q, us* __restrict__ FkB, us* __restrict__ FvB, int N)
{
    __shared__ float xL[8][CDIM];
    int row0 = blockIdx.x * 8;
    int t = threadIdx.x;
    for (int o = t; o < 8 * CDIM; o += 384) {
        int r = o >> 7, c = o & 127;
        int row = row0 + r;
        xL[r][c] = (row < N) ? F[row * CDIM + c] : 0.f;
    }
    __syncthreads();

    int e = t;  // 0..383
    const float4* WT4 = (const float4*)WT;
    float acc[8] = {0.f,0.f,0.f,0.f,0.f,0.f,0.f,0.f};
    #pragma unroll 8
    for (int c4 = 0; c4 < CDIM / 4; ++c4) {
        float4 w = WT4[c4 * 384 + e];
        #pragma unroll
        for (int r = 0; r < 8; ++r) {
            const float* x = &xL[r][c4 * 4];
            acc[r] += x[0]*w.x + x[1]*w.y + x[2]*w.z + x[3]*w.w;
        }
    }
    float bv = B[e];
    if (e < 128) {
        #pragma unroll
        for (int r = 0; r < 8; ++r) {
            int row = row0 + r;
            if (row < N) Q[row * CDIM + e] = acc[r] + bv;
        }
    } else if (e < 256) {
        int eo = e - 128;
        #pragma unroll
        for (int r = 0; r < 8; ++r) {
            int row = row0 + r;
            if (row < N) FkB[(size_t)row * CDIM + eo] = f2bf(acc[r] + bv);
        }
    } else {
        int eo = e - 256;
        #pragma unroll
        for (int r = 0; r < 8; ++r) {
            int row = row0 + r;
            if (row < N) FvB[(size_t)row * CDIM + eo] = f2bf(acc[r] + bv);
        }
    }
}

// ---------------------------------------------------------------------------
// K2: attention (R9/R11-verbatim; best measured ~703-710 us, no spill).
// ---------------------------------------------------------------------------
__global__ __launch_bounds__(256, 4) void k_attn(
    const float* __restrict__ coords, const int* __restrict__ kidx,
    const u8* __restrict__ kmask_u8, const int* __restrict__ kmask_i32,
    const int* __restrict__ maskflag,
    const float* __restrict__ Q, const us* __restrict__ FkB,
    const us* __restrict__ FvB,
    const float* __restrict__ wk, const float* __restrict__ wv,
    const float* __restrict__ kpw, const float* __restrict__ kpb,
    float* __restrict__ CTX)
{
    __shared__ __align__(16) u8 SM[14656];
    us*    qwH   = (us*)(SM);
    us*    qwL   = (us*)(SM + 2176);
    float* scL   = (float*)(SM + 4352);
    float* Ql    = (float*)(SM + 6016);
    float* rel   = (float*)(SM + 6528);
    float* kpw0S = (float*)(SM + 7104);
    float* kpw1S = (float*)(SM + 7616);
    float* kpw2S = (float*)(SM + 8128);
    float* kpbS  = (float*)(SM + 8640);
    int*   idxl  = (int*)  (SM + 9152);
    u8*    mskl  = (u8*)   (SM + 9344);
    float* Pb    = (float*)(SM + 9408);
    float* pc    = (float*)(SM + 13632);

    int n = blockIdx.x;
    int t = threadIdx.x;
    int w = t >> 6, lane = t & 63;

    if (t < KNBR) {
        int idx = kidx[n * KNBR + t];
        idxl[t] = idx;
        mskl[t] = maskflag[0] ? kmask_u8[n * KNBR + t]
                              : (u8)kmask_i32[n * KNBR + t];
        rel[t * 3 + 0] = coords[idx * 3 + 0] - coords[n * 3 + 0];
        rel[t * 3 + 1] = coords[idx * 3 + 1] - coords[n * 3 + 1];
        rel[t * 3 + 2] = coords[idx * 3 + 2] - coords[n * 3 + 2];
    }
    if (t < 128) {
        kpw0S[t] = kpw[t * 3 + 0];
        kpw1S[t] = kpw[t * 3 + 1];
        kpw2S[t] = kpw[t * 3 + 2];
        kpbS[t]  = kpb[t];
    } else {
        Ql[t - 128] = Q[n * CDIM + (t - 128)];
    }
    __syncthreads();

    {
        int h = t >> 5, c4 = t & 31;
        const float* qh = Ql + h * DHEAD;
        float a0=0.f, a1=0.f, a2=0.f, a3=0.f;
        #pragma unroll
        for (int d = 0; d < DHEAD; ++d) {
            float q = qh[d];
            float4 wr = *(const float4*)(wk + (size_t)(h * DHEAD + d) * CDIM + c4 * 4);
            a0 += q * wr.x; a1 += q * wr.y; a2 += q * wr.z; a3 += q * wr.w;
        }
        uint2 ph, pl;
        ph.x = cvtpk(a0, a1);
        ph.y = cvtpk(a2, a3);
        pl.x = cvtpk(a0 - blo32(ph.x), a1 - bhi32(ph.x));
        pl.y = cvtpk(a2 - blo32(ph.y), a3 - bhi32(ph.y));
        *(uint2*)&qwH[h * 136 + c4 * 4] = ph;
        *(uint2*)&qwL[h * 136 + c4 * 4] = pl;
    }

    union U8 { bf16x8 v; u32 wd[4]; };
    U8 BH[4], BL[4];
    if (w < 3) {
        int kk = w * 16 + (lane & 15);
        int cb0 = (lane >> 4) * 8;
        float r0 = rel[kk * 3], r1 = rel[kk * 3 + 1], r2 = rel[kk * 3 + 2];
        #pragma unroll
        for (int s = 0; s < 4; ++s) {
            int cb = cb0 + s * 32;
            float4 x0 = *(const float4*)&kpw0S[cb], x1 = *(const float4*)&kpw0S[cb + 4];
            float4 y0 = *(const float4*)&kpw1S[cb], y1 = *(const float4*)&kpw1S[cb + 4];
            float4 z0 = *(const float4*)&kpw2S[cb], z1 = *(const float4*)&kpw2S[cb + 4];
            float4 b0 = *(const float4*)&kpbS[cb],  b1 = *(const float4*)&kpbS[cb + 4];
            float p[8];
            p[0] = fmaxf(b0.x + r0*x0.x + r1*y0.x + r2*z0.x, 0.f);
            p[1] = fmaxf(b0.y + r0*x0.y + r1*y0.y + r2*z0.y, 0.f);
            p[2] = fmaxf(b0.z + r0*x0.z + r1*y0.z + r2*z0.z, 0.f);
            p[3] = fmaxf(b0.w + r0*x0.w + r1*y0.w + r2*z0.w, 0.f);
            p[4] = fmaxf(b1.x + r0*x1.x + r1*y1.x + r2*z1.x, 0.f);
            p[5] = fmaxf(b1.y + r0*x1.y + r1*y1.y + r2*z1.y, 0.f);
            p[6] = fmaxf(b1.z + r0*x1.z + r1*y1.z + r2*z1.z, 0.f);
            p[7] = fmaxf(b1.w + r0*x1.w + r1*y1.w + r2*z1.w, 0.f);
            #pragma unroll
            for (int j = 0; j < 4; ++j) {
                u32 hh = cvtpk(p[2*j], p[2*j+1]);
                BH[s].wd[j] = hh;
                BL[s].wd[j] = cvtpk(p[2*j] - blo32(hh), p[2*j+1] - bhi32(hh));
            }
        }
    } else {
        #pragma unroll
        for (int i = 0; i < 6; ++i) {
            int o = lane * 6 + i;
            int k = o >> 3, h = o & 7;
            const float* qh = Ql + h * DHEAD;
            const uint4* fk = (const uint4*)(FkB + (size_t)idxl[k] * CDIM + h * DHEAD);
            uint4 fa = fk[0], fb = fk[1];
            float s = qh[0]*blo32(fa.x) + qh[1]*bhi32(fa.x)
                    + qh[2]*blo32(fa.y) + qh[3]*bhi32(fa.y)
                    + qh[4]*blo32(fa.z) + qh[5]*bhi32(fa.z)
                    + qh[6]*blo32(fa.w) + qh[7]*bhi32(fa.w)
                    + qh[8]*blo32(fb.x) + qh[9]*bhi32(fb.x)
                    + qh[10]*blo32(fb.y) + qh[11]*bhi32(fb.y)
                    + qh[12]*blo32(fb.z) + qh[13]*bhi32(fb.z)
                    + qh[14]*blo32(fb.w) + qh[15]*bhi32(fb.w);
            scL[h * 52 + k] = s;
        }
    }
    __syncthreads();

    if (w < 3) {
        f32x4 acc = {0.f, 0.f, 0.f, 0.f};
        int arow = lane & 15;
        int ko = (lane >> 4) * 8;
        bool aval = arow < 8;
        bf16x8 zz = {0,0,0,0,0,0,0,0};
        #pragma unroll
        for (int s = 0; s < 4; ++s) {
            int c0 = s * 32 + ko;
            bf16x8 ah = aval ? *(const bf16x8*)(qwH + arow * 136 + c0) : zz;
            bf16x8 al = aval ? *(const bf16x8*)(qwL + arow * 136 + c0) : zz;
            acc = __builtin_amdgcn_mfma_f32_16x16x32_bf16(ah, BH[s].v, acc, 0, 0, 0);
            acc = __builtin_amdgcn_mfma_f32_16x16x32_bf16(ah, BL[s].v, acc, 0, 0, 0);
            acc = __builtin_amdgcn_mfma_f32_16x16x32_bf16(al, BH[s].v, acc, 0, 0, 0);
        }
        if (lane < 32) {
            int kk = w * 16 + (lane & 15);
            int rb = (lane >> 4) * 4;
            u8 mk = mskl[kk];
            #pragma unroll
            for (int j = 0; j < 4; ++j) {
                int h = rb + j;
                float s = acc[j] + scL[h * 52 + kk];
                scL[h * 52 + kk] = mk ? -1e30f : s * 0.25f;
            }
        }
    }
    __syncthreads();

    {
        int h = t >> 5, l32 = t & 31;
        float* sc = scL + h * 52;
        float v0 = sc[l32];
        float v1 = (l32 < KNBR - 32) ? sc[l32 + 32] : -1e30f;
        float m = fmaxf(v0, v1);
        #pragma unroll
        for (int off = 16; off >= 1; off >>= 1)
            m = fmaxf(m, __shfl_xor(m, off, 32));
        float e0 = __expf(v0 - m);
        float e1 = (l32 < KNBR - 32) ? __expf(v1 - m) : 0.f;
        float s = e0 + e1;
        #pragma unroll
        for (int off = 16; off >= 1; off >>= 1)
            s += __shfl_xor(s, off, 32);
        float inv = 1.f / s;
        sc[l32] = e0 * inv;
        if (l32 < KNBR - 32) sc[l32 + 32] = e1 * inv;
    }
    __syncthreads();

    {
        bf16x8 AH[2], AL[2];
        int arow = lane & 15;
        bool av = arow < 8;
        #pragma unroll
        for (int st = 0; st < 2; ++st) {
            int k0 = (lane >> 4) * 8 + st * 32;
            float pr[8];
            if (av && k0 < KNBR) {
                float4 s0 = *(const float4*)&scL[arow * 52 + k0];
                float4 s1 = *(const float4*)&scL[arow * 52 + k0 + 4];
                pr[0]=s0.x; pr[1]=s0.y; pr[2]=s0.z; pr[3]=s0.w;
                pr[4]=s1.x; pr[5]=s1.y; pr[6]=s1.z; pr[7]=s1.w;
            } else {
                #pragma unroll
                for (int j = 0; j < 8; ++j) pr[j] = 0.f;
            }
            U8 ah, al;
            #pragma unroll
            for (int j = 0; j < 4; ++j) {
                u32 hh = cvtpk(pr[2*j], pr[2*j+1]);
                ah.wd[j] = hh;
                al.wd[j] = cvtpk(pr[2*j] - blo32(hh), pr[2*j+1] - bhi32(hh));
            }
            AH[st] = ah.v; AL[st] = al.v;
        }
        #pragma unroll
        for (int ct = 0; ct < 2; ++ct) {
            int c = w * 32 + ct * 16 + (lane & 15);
            float w0 = kpw0S[c], w1 = kpw1S[c], w2 = kpw2S[c], bb = kpbS[c];
            f32x4 acc = {0.f, 0.f, 0.f, 0.f};
            #pragma unroll
            for (int st = 0; st < 2; ++st) {
                int k0 = (lane >> 4) * 8 + st * 32;
                U8 bh;
                if (k0 < KNBR) {
                    #pragma unroll
                    for (int j = 0; j < 4; ++j) {
                        const float* ra = rel + (k0 + 2*j) * 3;
                        const float* rb = rel + (k0 + 2*j + 1) * 3;
                        float pa = fmaxf(bb + ra[0]*w0 + ra[1]*w1 + ra[2]*w2, 0.f);
                        float pb = fmaxf(bb + rb[0]*w0 + rb[1]*w1 + rb[2]*w2, 0.f);
                        bh.wd[j] = cvtpk(pa, pb);
                    }
                } else {
                    bh.wd[0]=bh.wd[1]=bh.wd[2]=bh.wd[3]=0u;
                }
                acc = __builtin_amdgcn_mfma_f32_16x16x32_bf16(AH[st], bh.v, acc, 0, 0, 0);
                acc = __builtin_amdgcn_mfma_f32_16x16x32_bf16(AL[st], bh.v, acc, 0, 0, 0);
            }
            if (lane < 32) {
                int rb2 = (lane >> 4) * 4;
                #pragma unroll
                for (int j = 0; j < 4; ++j)
                    Pb[(rb2 + j) * 132 + c] = acc[j];
            }
        }
    }
    __syncthreads();

    {
        int c = t & 127, half = t >> 7;
        int h = c >> 4;
        const float* sc = scL + h * 52;
        float accF = 0.f;
        #pragma unroll 4
        for (int kk = 0; kk < 24; ++kk) {
            int k = half * 24 + kk;
            accF += sc[k] * bf2f(FvB[(size_t)idxl[k] * CDIM + c]);
        }
        const float4* wr = (const float4*)(wv + (size_t)c * CDIM) + half * 16;
        const float4* pb4 = (const float4*)(Pb + h * 132) + half * 16;
        #pragma unroll 4
        for (int j = 0; j < 16; ++j) {
            float4 wq = wr[j], p = pb4[j];
            accF += wq.x*p.x + wq.y*p.y + wq.z*p.z + wq.w*p.w;
        }
        pc[half * 128 + c] = accF;
    }
    __syncthreads();
    if (t < CDIM) CTX[n * CDIM + t] = pc[t] + pc[128 + t];
}

// ---------------------------------------------------------------------------
// K3/K6: 128->128 GEMM (bf16 MFMA) + bias (+res f32) + LN (+relu).
// 16 rows/block, 4 waves x 2 col-tiles. Fragment mapping = k_attn-validated:
// A row=lane&15, k=(lane>>4)*8+s*32; B row=lane&15 (e); D col=e, row=(lane>>4)*4+j.
// ---------------------------------------------------------------------------
__global__ __launch_bounds__(256) void k_proj_ln_m(
    const float* __restrict__ X, const float* __restrict__ RES,
    const us* __restrict__ WB, const float* __restrict__ B,
    const float* __restrict__ G, const float* __restrict__ LB,
    float* __restrict__ OUT, int N, int relu_out)
{
    __shared__ us xB[16 * 136];           // bf16 x rows
    __shared__ float aL[16][CDIM + 4];
    __shared__ float mu[16], rs[16];
    int row0 = blockIdx.x * 16;
    int t = threadIdx.x;
    {   // stage + convert: thread -> 8 bf16 of one row
        int r = t >> 4, cb = (t & 15) * 8;
        int row = row0 + r;
        uint4 o = make_uint4(0, 0, 0, 0);
        if (row < N) {
            float4 v0 = *(const float4*)&X[(size_t)row * CDIM + cb];
            float4 v1 = *(const float4*)&X[(size_t)row * CDIM + cb + 4];
            o.x = cvtpk(v0.x, v0.y); o.y = cvtpk(v0.z, v0.w);
            o.z = cvtpk(v1.x, v1.y); o.w = cvtpk(v1.z, v1.w);
        }
        *(uint4*)&xB[r * 136 + cb] = o;
    }
    __syncthreads();

    int w = t >> 6, lane = t & 63;
    int arow = lane & 15, ko = (lane >> 4) * 8;
    bf16x8 afr[4];
    #pragma unroll
    for (int s = 0; s < 4; ++s)
        afr[s] = *(const bf16x8*)&xB[arow * 136 + s * 32 + ko];

    #pragma unroll
    for (int ct = 0; ct < 2; ++ct) {
        int e0 = (w * 2 + ct) * 16;
        f32x4 acc = {0.f, 0.f, 0.f, 0.f};
        #pragma unroll
        for (int s = 0; s < 4; ++s) {
            bf16x8 bfr = *(const bf16x8*)&WB[(size_t)(e0 + arow) * CDIM + s * 32 + ko];
            acc = __builtin_amdgcn_mfma_f32_16x16x32_bf16(afr[s], bfr, acc, 0, 0, 0);
        }
        int e = e0 + arow;
        float bb = B[e];
        #pragma unroll
        for (int jj = 0; jj < 4; ++jj) {
            int r = (lane >> 4) * 4 + jj;
            int row = row0 + r;
            float a = acc[jj] + bb;
            if (RES != nullptr && row < N) a += RES[(size_t)row * CDIM + e];
            aL[r][e] = a;
        }
    }
    __syncthreads();

    {   // LN stats (R11-identical)
        int r = t >> 4, j = t & 15;
        float s = 0.f;
        #pragma unroll
        for (int jj = 0; jj < 8; ++jj) s += aL[r][j * 8 + jj];
        #pragma unroll
        for (int off = 8; off >= 1; off >>= 1) s += __shfl_xor(s, off, 16);
        float mean = s * (1.f / 128.f);
        float v = 0.f;
        #pragma unroll
        for (int jj = 0; jj < 8; ++jj) {
            float d = aL[r][j * 8 + jj] - mean; v += d * d;
        }
        #pragma unroll
        for (int off = 8; off >= 1; off >>= 1) v += __shfl_xor(v, off, 16);
        if (j == 0) { mu[r] = mean; rs[r] = rsqrtf(v * (1.f / 128.f) + 1e-5f); }
    }
    __syncthreads();

    for (int o = t; o < 16 * CDIM; o += 256) {
        int r = o >> 7, c = o & 127;
        int row = row0 + r;
        if (row < N) {
            float y = (aL[r][c] - mu[r]) * rs[r] * G[c] + LB[c];
            if (relu_out) y = fmaxf(y, 0.f);
            OUT[row * CDIM + c] = y;
        }
    }
}

// ---------------------------------------------------------------------------
// K4: ff1 = relu(x @ W1^T + b1) -> HID (bf16), 128 -> 256, bf16 MFMA.
// 16 rows/block, 4 waves x 4 col-tiles.
// ---------------------------------------------------------------------------
__global__ __launch_bounds__(256) void k_ff1_m(
    const float* __restrict__ X, const us* __restrict__ WB,
    const float* __restrict__ B, us* __restrict__ HID, int N)
{
    __shared__ us xB[16 * 136];
    int row0 = blockIdx.x * 16;
    int t = threadIdx.x;
    {
        int r = t >> 4, cb = (t & 15) * 8;
        int row = row0 + r;
        uint4 o = make_uint4(0, 0, 0, 0);
        if (row < N) {
            float4 v0 = *(const float4*)&X[(size_t)row * CDIM + cb];
            float4 v1 = *(const float4*)&X[(size_t)row * CDIM + cb + 4];
            o.x = cvtpk(v0.x, v0.y); o.y = cvtpk(v0.z, v0.w);
            o.z = cvtpk(v1.x, v1.y); o.w = cvtpk(v1.z, v1.w);
        }
        *(uint4*)&xB[r * 136 + cb] = o;
    }
    __syncthreads();

    int w = t >> 6, lane = t & 63;
    int arow = lane & 15, ko = (lane >> 4) * 8;
    bf16x8 afr[4];
    #pragma unroll
    for (int s = 0; s < 4; ++s)
        afr[s] = *(const bf16x8*)&xB[arow * 136 + s * 32 + ko];

    #pragma unroll
    for (int ct = 0; ct < 4; ++ct) {
        int e0 = (w * 4 + ct) * 16;
        f32x4 acc = {0.f, 0.f, 0.f, 0.f};
        #pragma unroll
        for (int s = 0; s < 4; ++s) {
            bf16x8 bfr = *(const bf16x8*)&WB[(size_t)(e0 + arow) * CDIM + s * 32 + ko];
            acc = __builtin_amdgcn_mfma_f32_16x16x32_bf16(afr[s], bfr, acc, 0, 0, 0);
        }
        int e = e0 + arow;
        float bb = B[e];
        #pragma unroll
        for (int jj = 0; jj < 4; ++jj) {
            int r = (lane >> 4) * 4 + jj;
            int row = row0 + r;
            if (row < N)
                HID[(size_t)row * FFDIM + e] = f2bf(fmaxf(acc[jj] + bb, 0.f));
        }
    }
}

// ---------------------------------------------------------------------------
// K5: x2 = LN(x1 + hid @ W2^T + b2), 256 -> 128, bf16 MFMA (hid already bf16).
// 16 rows/block, 4 waves x 2 col-tiles, K=256 (8 steps).
// ---------------------------------------------------------------------------
__global__ __launch_bounds__(256) void k_ff2_ln_m(
    const us* __restrict__ HID, const float* __restrict__ RES,
    const us* __restrict__ WB, const float* __restrict__ B,
    const float* __restrict__ G, const float* __restrict__ LB,
    float* __restrict__ OUT, int N)
{
    __shared__ us xB[16 * 264];           // 16 rows x 256 bf16 (+8 pad)
    __shared__ float aL[16][CDIM + 4];
    __shared__ float mu[16], rs[16];
    int row0 = blockIdx.x * 16;
    int t = threadIdx.x;
    {   // stage: thread -> 16 bf16 of one row (already bf16 in HID)
        int r = t >> 4, cb = (t & 15) * 16;
        int row = row0 + r;
        uint4 o0 = make_uint4(0,0,0,0), o1 = make_uint4(0,0,0,0);
        if (row < N) {
            const uint4* hp = (const uint4*)&HID[(size_t)row * FFDIM + cb];
            o0 = hp[0]; o1 = hp[1];
        }
        *(uint4*)&xB[r * 264 + cb] = o0;
        *(uint4*)&xB[r * 264 + cb + 8] = o1;
    }
    __syncthreads();

    int w = t >> 6, lane = t & 63;
    int arow = lane & 15, ko = (lane >> 4) * 8;
    #pragma unroll
    for (int ct = 0; ct < 2; ++ct) {
        int e0 = (w * 2 + ct) * 16;
        f32x4 acc = {0.f, 0.f, 0.f, 0.f};
        #pragma unroll
        for (int s = 0; s < 8; ++s) {
            bf16x8 af = *(const bf16x8*)&xB[arow * 264 + s * 32 + ko];
            bf16x8 bfr = *(const bf16x8*)&WB[(size_t)(e0 + arow) * FFDIM + s * 32 + ko];
            acc = __builtin_amdgcn_mfma_f32_16x16x32_bf16(af, bfr, acc, 0, 0, 0);
        }
        int e = e0 + arow;
        float bb = B[e];
        #pragma unroll
        for (int jj = 0; jj < 4; ++jj) {
            int r = (lane >> 4) * 4 + jj;
            int row = row0 + r;
            float a = acc[jj] + bb;
            if (row < N) a += RES[(size_t)row * CDIM + e];
            aL[r][e] = a;
        }
    }
    __syncthreads();

    {
        int r = t >> 4, j = t & 15;
        float s = 0.f;
        #pragma unroll
        for (int jj = 0; jj < 8; ++jj) s += aL[r][j * 8 + jj];
        #pragma unroll
        for (int off = 8; off >= 1; off >>= 1) s += __shfl_xor(s, off, 16);
        float mean = s * (1.f / 128.f);
        float v = 0.f;
        #pragma unroll
        for (int jj = 0; jj < 8; ++jj) {
            float d = aL[r][j * 8 + jj] - mean; v += d * d;
        }
        #pragma unroll
        for (int off = 8; off >= 1; off >>= 1) v += __shfl_xor(v, off, 16);
        if (j == 0) { mu[r] = mean; rs[r] = rsqrtf(v * (1.f / 128.f) + 1e-5f); }
    }
    __syncthreads();

    for (int o = t; o < 16 * CDIM; o += 256) {
        int r = o >> 7, c = o & 127;
        int row = row0 + r;
        if (row < N)
            OUT[row * CDIM + c] = (aL[r][c] - mu[r]) * rs[r] * G[c] + LB[c];
    }
}

// ---------------------------------------------------------------------------
extern "C" void kernel_launch(void* const* d_in, const int* in_sizes, int n_in,
                              void* d_out, int out_size, void* d_ws, size_t ws_size,
                              hipStream_t stream)
{
    const float* F      = (const float*)d_in[0];
    const float* coords = (const float*)d_in[1];
    const int*   kidx   = (const int*)d_in[2];
    const void*  kmask  = d_in[3];
    const float* ipw    = (const float*)d_in[4];
    const float* ipb    = (const float*)d_in[5];
    const float* opw    = (const float*)d_in[6];
    const float* opb    = (const float*)d_in[7];
    const float* kpw    = (const float*)d_in[8];
    const float* kpb    = (const float*)d_in[9];
    const float* ln1g   = (const float*)d_in[10];
    const float* ln1b   = (const float*)d_in[11];
    const float* ln2g   = (const float*)d_in[12];
    const float* ln2b   = (const float*)d_in[13];
    const float* w1     = (const float*)d_in[14];
    const float* b1     = (const float*)d_in[15];
    const float* w2     = (const float*)d_in[16];
    const float* b2     = (const float*)d_in[17];
    const float* ow     = (const float*)d_in[18];
    const float* ob     = (const float*)d_in[19];
    const float* ln3g   = (const float*)d_in[20];
    const float* ln3b   = (const float*)d_in[21];

    int N = in_sizes[0] / CDIM;
    size_t NC = (size_t)N * CDIM;

    float* ws  = (float*)d_ws;
    // layout (floats):
    //   [0,   NC)    Q  (later X1)
    //   [NC,  1.5NC) FkB (bf16)  } HID (bf16, N*256 us) = [NC,2NC) after attn
    //   [1.5NC,2NC)  FvB (bf16)  }
    //   [2NC, 3NC)   CTX
    //   [3NC, 4NC)   X2
    //   [4NC, ...)   WTq(49152 f) | WBo,WB1,WB2,WBw (bf16) | mflag
    float* Q    = ws;
    us*    FkB  = (us*)(ws + NC);
    us*    FvB  = (us*)(ws + NC) + NC;
    float* CTX  = ws + 2 * NC;
    float* X1   = Q;
    us*    HID  = (us*)(ws + NC);        // N*256 us over FkB+FvB (dead post-attn)
    float* X2   = ws + 3 * NC;
    float* WTq  = ws + 4 * NC;           // 384*128 f32
    us*    WBo  = (us*)(WTq + 384 * 128);   // 128*128
    us*    WB1  = WBo + 128 * 128;          // 256*128
    us*    WB2  = WB1 + 256 * 128;          // 128*256
    us*    WBw  = WB2 + 128 * 256;          // 128*128
    int*   mflag = (int*)(WBw + 128 * 128);

    const float* wk = ipw + CDIM * CDIM;
    const float* wv = ipw + 2 * CDIM * CDIM;

    hipMemsetAsync(mflag, 0, sizeof(int), stream);
    int nwords = (N * KNBR) / 4;
    k_mask_probe<<<256, 256, 0, stream>>>((const u32*)kmask, nwords, mflag);

    // one-time weight prep
    k_wt<<<(384 * 32 + 255) / 256, 256, 0, stream>>>(ipw, WTq, 384, 32);
    k_wb<<<(128 * 64 + 255) / 256, 256, 0, stream>>>(opw, WBo, 128 * 64);
    k_wb<<<(256 * 64 + 255) / 256, 256, 0, stream>>>(w1,  WB1, 256 * 64);
    k_wb<<<(128 * 128 + 255) / 256, 256, 0, stream>>>(w2, WB2, 128 * 128);
    k_wb<<<(128 * 64 + 255) / 256, 256, 0, stream>>>(ow,  WBw, 128 * 64);

    k_qkv<<<(N + 7) / 8, 384, 0, stream>>>(F, WTq, ipb, Q, FkB, FvB, N);
    k_attn<<<N, 256, 0, stream>>>(coords, kidx, (const u8*)kmask,
                                  (const int*)kmask, mflag, Q, FkB, FvB,
                                  wk, wv, kpw, kpb, CTX);
    k_proj_ln_m<<<(N + 15) / 16, 256, 0, stream>>>(CTX, F, WBo, opb,
                                                   ln1g, ln1b, X1, N, 0);
    k_ff1_m<<<(N + 15) / 16, 256, 0, stream>>>(X1, WB1, b1, HID, N);
    k_ff2_ln_m<<<(N + 15) / 16, 256, 0, stream>>>(HID, X1, WB2, b2,
                                                  ln2g, ln2b, X2, N);
    k_proj_ln_m<<<(N + 15) / 16, 256, 0, stream>>>(X2, nullptr, WBw, ob,
                                                   ln3g, ln3b, (float*)d_out, N, 1);
}

// Round 13
// 832.164 us; speedup vs baseline: 1.5380x; 1.0463x over previous
//
#include <hip/hip_runtime.h>
#include <stdint.h>

typedef unsigned char u8;
typedef unsigned short us;
typedef unsigned int u32;

#define CDIM  128
#define KNBR  48
#define HEADS 8
#define DHEAD 16
#define FFDIM 256

using bf16x8 = __attribute__((ext_vector_type(8))) short;  // 8 bf16 (4 VGPRs)
using f32x4  = __attribute__((ext_vector_type(4))) float;  // 4 fp32

__device__ inline float blo32(u32 u) { union { u32 i; float f; } v; v.i = u << 16; return v.f; }
__device__ inline float bhi32(u32 u) { union { u32 i; float f; } v; v.i = u & 0xFFFF0000u; return v.f; }
__device__ inline float bf2f(us u) { union { u32 i; float f; } v; v.i = ((u32)u) << 16; return v.f; }
__device__ inline us f2bf(float x) {
    union { float f; u32 i; } v; v.f = x;
    u32 r = v.i + 0x7FFFu + ((v.i >> 16) & 1u);
    return (us)(r >> 16);
}
// HW packed f32x2 -> bf16x2 (RNE), one instruction (gfx950; no builtin).
__device__ inline u32 cvtpk(float a, float b) {
    u32 r;
    asm("v_cvt_pk_bf16_f32 %0, %1, %2" : "=v"(r) : "v"(a), "v"(b));
    return r;
}

// ---------------------------------------------------------------------------
// K0: probe key_mask storage (int32 vs u8 bool). flag=1 -> u8 storage.
// ---------------------------------------------------------------------------
__global__ void k_mask_probe(const u32* __restrict__ mw, int nwords,
                             int* __restrict__ flag)
{
    u32 any = 0;
    for (int j = blockIdx.x * blockDim.x + threadIdx.x; j < nwords;
         j += gridDim.x * blockDim.x)
        any |= mw[j] & 0xFFFFFF00u;
    if (any) atomicOr(flag, 1);
}

// ---------------------------------------------------------------------------
// K0b: f32 W -> WT4[c4][e] float4-transpose (for k_qkv's coalesced loads).
// ---------------------------------------------------------------------------
__global__ __launch_bounds__(256) void k_wt(
    const float* __restrict__ W, float* __restrict__ WT, int E, int C4)
{
    int i = blockIdx.x * 256 + threadIdx.x;
    if (i < E * C4) {
        int e = i / C4, c4 = i - e * C4;
        float4 v = *(const float4*)(W + (size_t)e * (C4 * 4) + c4 * 4);
        ((float4*)WT)[(size_t)c4 * E + e] = v;
    }
}

// ---------------------------------------------------------------------------
// K0c: f32 W -> bf16 row-major (for the tail MFMA GEMMs). n = elems/2.
// ---------------------------------------------------------------------------
__global__ __launch_bounds__(256) void k_wb(
    const float* __restrict__ W, us* __restrict__ WB, int n2)
{
    int i = blockIdx.x * 256 + threadIdx.x;
    if (i < n2) {
        float2 v = *(const float2*)(W + (size_t)i * 2);
        ((u32*)WB)[i] = cvtpk(v.x, v.y);
    }
}

// ---------------------------------------------------------------------------
// K1: QKV projection (coalesced WT). Q f32; Fk/Fv bf16.
// ---------------------------------------------------------------------------
__global__ __launch_bounds__(384) void k_qkv(
    const float* __restrict__ F, const float* __restrict__ WT,
    const float* __restrict__ B,
    float* __restrict__ Q, us* __restrict__ FkB, us* __restrict__ FvB, int N)
{
    __shared__ float xL[8][CDIM];
    int row0 = blockIdx.x * 8;
    int t = threadIdx.x;
    for (int o = t; o < 8 * CDIM; o += 384) {
        int r = o >> 7, c = o & 127;
        int row = row0 + r;
        xL[r][c] = (row < N) ? F[row * CDIM + c] : 0.f;
    }
    __syncthreads();

    int e = t;  // 0..383
    const float4* WT4 = (const float4*)WT;
    float acc[8] = {0.f,0.f,0.f,0.f,0.f,0.f,0.f,0.f};
    #pragma unroll 8
    for (int c4 = 0; c4 < CDIM / 4; ++c4) {
        float4 w = WT4[c4 * 384 + e];
        #pragma unroll
        for (int r = 0; r < 8; ++r) {
            const float* x = &xL[r][c4 * 4];
            acc[r] += x[0]*w.x + x[1]*w.y + x[2]*w.z + x[3]*w.w;
        }
    }
    float bv = B[e];
    if (e < 128) {
        #pragma unroll
        for (int r = 0; r < 8; ++r) {
            int row = row0 + r;
            if (row < N) Q[row * CDIM + e] = acc[r] + bv;
        }
    } else if (e < 256) {
        int eo = e - 128;
        #pragma unroll
        for (int r = 0; r < 8; ++r) {
            int row = row0 + r;
            if (row < N) FkB[(size_t)row * CDIM + eo] = f2bf(acc[r] + bv);
        }
    } else {
        int eo = e - 256;
        #pragma unroll
        for (int r = 0; r < 8; ++r) {
            int row = row0 + r;
            if (row < N) FvB[(size_t)row * CDIM + eo] = f2bf(acc[r] + bv);
        }
    }
}

// ---------------------------------------------------------------------------
// K2: attention. R12 structure with two reg-focused edits:
//  (a) __launch_bounds__(256,6): VGPR_Count=60 fits the 85-reg budget now
//      (cvtpk cut pressure); lifts occupancy cap 50% -> 75%. Spill sentinel:
//      WRITE_SIZE (R7 spill showed as 25MB->975MB).
//  (b) phase B2/C fused: P-fragment chunk s built then immediately MFMA'd —
//      8 live fragment VGPRs instead of 32. Bit-identical math.
// ---------------------------------------------------------------------------
__global__ __launch_bounds__(256, 6) void k_attn(
    const float* __restrict__ coords, const int* __restrict__ kidx,
    const u8* __restrict__ kmask_u8, const int* __restrict__ kmask_i32,
    const int* __restrict__ maskflag,
    const float* __restrict__ Q, const us* __restrict__ FkB,
    const us* __restrict__ FvB,
    const float* __restrict__ wk, const float* __restrict__ wv,
    const float* __restrict__ kpw, const float* __restrict__ kpb,
    float* __restrict__ CTX)
{
    __shared__ __align__(16) u8 SM[14656];
    us*    qwH   = (us*)(SM);
    us*    qwL   = (us*)(SM + 2176);
    float* scL   = (float*)(SM + 4352);
    float* Ql    = (float*)(SM + 6016);
    float* rel   = (float*)(SM + 6528);
    float* kpw0S = (float*)(SM + 7104);
    float* kpw1S = (float*)(SM + 7616);
    float* kpw2S = (float*)(SM + 8128);
    float* kpbS  = (float*)(SM + 8640);
    int*   idxl  = (int*)  (SM + 9152);
    u8*    mskl  = (u8*)   (SM + 9344);
    float* Pb    = (float*)(SM + 9408);
    float* pc    = (float*)(SM + 13632);

    int n = blockIdx.x;
    int t = threadIdx.x;
    int w = t >> 6, lane = t & 63;

    // ---- phase A ----
    if (t < KNBR) {
        int idx = kidx[n * KNBR + t];
        idxl[t] = idx;
        mskl[t] = maskflag[0] ? kmask_u8[n * KNBR + t]
                              : (u8)kmask_i32[n * KNBR + t];
        rel[t * 3 + 0] = coords[idx * 3 + 0] - coords[n * 3 + 0];
        rel[t * 3 + 1] = coords[idx * 3 + 1] - coords[n * 3 + 1];
        rel[t * 3 + 2] = coords[idx * 3 + 2] - coords[n * 3 + 2];
    }
    if (t < 128) {
        kpw0S[t] = kpw[t * 3 + 0];
        kpw1S[t] = kpw[t * 3 + 1];
        kpw2S[t] = kpw[t * 3 + 2];
        kpbS[t]  = kpb[t];
    } else {
        Ql[t - 128] = Q[n * CDIM + (t - 128)];
    }
    __syncthreads();

    // ---- phase B1: qw = q_h @ wk_h (f32 -> hi/lo bf16 in LDS, 8 rows) ----
    {
        int h = t >> 5, c4 = t & 31;
        const float* qh = Ql + h * DHEAD;
        float a0=0.f, a1=0.f, a2=0.f, a3=0.f;
        #pragma unroll
        for (int d = 0; d < DHEAD; ++d) {
            float q = qh[d];
            float4 wr = *(const float4*)(wk + (size_t)(h * DHEAD + d) * CDIM + c4 * 4);
            a0 += q * wr.x; a1 += q * wr.y; a2 += q * wr.z; a3 += q * wr.w;
        }
        uint2 ph, pl;
        ph.x = cvtpk(a0, a1);
        ph.y = cvtpk(a2, a3);
        pl.x = cvtpk(a0 - blo32(ph.x), a1 - bhi32(ph.x));
        pl.y = cvtpk(a2 - blo32(ph.y), a3 - bhi32(ph.y));
        *(uint2*)&qwH[h * 136 + c4 * 4] = ph;
        *(uint2*)&qwL[h * 136 + c4 * 4] = pl;
    }

    // ---- phase B2 (wave 3 only): exact f32 q.Fk partial scores ----
    if (w == 3) {
        #pragma unroll
        for (int i = 0; i < 6; ++i) {
            int o = lane * 6 + i;
            int k = o >> 3, h = o & 7;
            const float* qh = Ql + h * DHEAD;
            const uint4* fk = (const uint4*)(FkB + (size_t)idxl[k] * CDIM + h * DHEAD);
            uint4 fa = fk[0], fb = fk[1];
            float s = qh[0]*blo32(fa.x) + qh[1]*bhi32(fa.x)
                    + qh[2]*blo32(fa.y) + qh[3]*bhi32(fa.y)
                    + qh[4]*blo32(fa.z) + qh[5]*bhi32(fa.z)
                    + qh[6]*blo32(fa.w) + qh[7]*bhi32(fa.w)
                    + qh[8]*blo32(fb.x) + qh[9]*bhi32(fb.x)
                    + qh[10]*blo32(fb.y) + qh[11]*bhi32(fb.y)
                    + qh[12]*blo32(fb.z) + qh[13]*bhi32(fb.z)
                    + qh[14]*blo32(fb.w) + qh[15]*bhi32(fb.w);
            scL[h * 52 + k] = s;
        }
    }
    __syncthreads();

    union U8 { bf16x8 v; u32 wd[4]; };

    // ---- phase C (fused): waves 0-2 build P chunk s in regs, MFMA it ----
    if (w < 3) {
        f32x4 acc = {0.f, 0.f, 0.f, 0.f};
        int kk = w * 16 + (lane & 15);        // P row this lane owns (B-frag)
        int cb0 = (lane >> 4) * 8;            // c-chunk base (= A k-offset)
        int arow = lane & 15;
        bool aval = arow < 8;
        bf16x8 zz = {0,0,0,0,0,0,0,0};
        float r0 = rel[kk * 3], r1 = rel[kk * 3 + 1], r2 = rel[kk * 3 + 2];
        #pragma unroll
        for (int s = 0; s < 4; ++s) {
            int cb = cb0 + s * 32;
            float4 x0 = *(const float4*)&kpw0S[cb], x1 = *(const float4*)&kpw0S[cb + 4];
            float4 y0 = *(const float4*)&kpw1S[cb], y1 = *(const float4*)&kpw1S[cb + 4];
            float4 z0 = *(const float4*)&kpw2S[cb], z1 = *(const float4*)&kpw2S[cb + 4];
            float4 b0 = *(const float4*)&kpbS[cb],  b1 = *(const float4*)&kpbS[cb + 4];
            float p[8];
            p[0] = fmaxf(b0.x + r0*x0.x + r1*y0.x + r2*z0.x, 0.f);
            p[1] = fmaxf(b0.y + r0*x0.y + r1*y0.y + r2*z0.y, 0.f);
            p[2] = fmaxf(b0.z + r0*x0.z + r1*y0.z + r2*z0.z, 0.f);
            p[3] = fmaxf(b0.w + r0*x0.w + r1*y0.w + r2*z0.w, 0.f);
            p[4] = fmaxf(b1.x + r0*x1.x + r1*y1.x + r2*z1.x, 0.f);
            p[5] = fmaxf(b1.y + r0*x1.y + r1*y1.y + r2*z1.y, 0.f);
            p[6] = fmaxf(b1.z + r0*x1.z + r1*y1.z + r2*z1.z, 0.f);
            p[7] = fmaxf(b1.w + r0*x1.w + r1*y1.w + r2*z1.w, 0.f);
            U8 bh, bl;
            #pragma unroll
            for (int j = 0; j < 4; ++j) {
                u32 hh = cvtpk(p[2*j], p[2*j+1]);
                bh.wd[j] = hh;
                bl.wd[j] = cvtpk(p[2*j] - blo32(hh), p[2*j+1] - bhi32(hh));
            }
            int c0 = s * 32 + cb0;
            bf16x8 ah = aval ? *(const bf16x8*)(qwH + arow * 136 + c0) : zz;
            bf16x8 al = aval ? *(const bf16x8*)(qwL + arow * 136 + c0) : zz;
            acc = __builtin_amdgcn_mfma_f32_16x16x32_bf16(ah, bh.v, acc, 0, 0, 0);
            acc = __builtin_amdgcn_mfma_f32_16x16x32_bf16(ah, bl.v, acc, 0, 0, 0);
            acc = __builtin_amdgcn_mfma_f32_16x16x32_bf16(al, bh.v, acc, 0, 0, 0);
        }
        // combine: D col=lane&15 -> kk, row=(lane>>4)*4+j -> h (rows 0-7 valid)
        if (lane < 32) {
            int kc = w * 16 + (lane & 15);
            int rb = (lane >> 4) * 4;
            u8 mk = mskl[kc];
            #pragma unroll
            for (int j = 0; j < 4; ++j) {
                int h = rb + j;
                float s = acc[j] + scL[h * 52 + kc];
                scL[h * 52 + kc] = mk ? -1e30f : s * 0.25f;
            }
        }
    }
    __syncthreads();

    // ---- phase D: softmax (32 lanes per head) ----
    {
        int h = t >> 5, l32 = t & 31;
        float* sc = scL + h * 52;
        float v0 = sc[l32];
        float v1 = (l32 < KNBR - 32) ? sc[l32 + 32] : -1e30f;
        float m = fmaxf(v0, v1);
        #pragma unroll
        for (int off = 16; off >= 1; off >>= 1)
            m = fmaxf(m, __shfl_xor(m, off, 32));
        float e0 = __expf(v0 - m);
        float e1 = (l32 < KNBR - 32) ? __expf(v1 - m) : 0.f;
        float s = e0 + e1;
        #pragma unroll
        for (int off = 16; off >= 1; off >>= 1)
            s += __shfl_xor(s, off, 32);
        float inv = 1.f / s;
        sc[l32] = e0 * inv;
        if (l32 < KNBR - 32) sc[l32 + 32] = e1 * inv;
    }
    __syncthreads();

    // ---- phase E: Pbar via MFMA; A=attn hi/lo, B=P-hi rebuilt in regs ----
    {
        bf16x8 AH[2], AL[2];
        int arow = lane & 15;
        bool av = arow < 8;
        #pragma unroll
        for (int st = 0; st < 2; ++st) {
            int k0 = (lane >> 4) * 8 + st * 32;
            float pr[8];
            if (av && k0 < KNBR) {
                float4 s0 = *(const float4*)&scL[arow * 52 + k0];
                float4 s1 = *(const float4*)&scL[arow * 52 + k0 + 4];
                pr[0]=s0.x; pr[1]=s0.y; pr[2]=s0.z; pr[3]=s0.w;
                pr[4]=s1.x; pr[5]=s1.y; pr[6]=s1.z; pr[7]=s1.w;
            } else {
                #pragma unroll
                for (int j = 0; j < 8; ++j) pr[j] = 0.f;
            }
            U8 ah, al;
            #pragma unroll
            for (int j = 0; j < 4; ++j) {
                u32 hh = cvtpk(pr[2*j], pr[2*j+1]);
                ah.wd[j] = hh;
                al.wd[j] = cvtpk(pr[2*j] - blo32(hh), pr[2*j+1] - bhi32(hh));
            }
            AH[st] = ah.v; AL[st] = al.v;
        }
        #pragma unroll
        for (int ct = 0; ct < 2; ++ct) {
            int c = w * 32 + ct * 16 + (lane & 15);
            float w0 = kpw0S[c], w1 = kpw1S[c], w2 = kpw2S[c], bb = kpbS[c];
            f32x4 acc = {0.f, 0.f, 0.f, 0.f};
            #pragma unroll
            for (int st = 0; st < 2; ++st) {
                int k0 = (lane >> 4) * 8 + st * 32;
                U8 bh;
                if (k0 < KNBR) {
                    #pragma unroll
                    for (int j = 0; j < 4; ++j) {
                        const float* ra = rel + (k0 + 2*j) * 3;
                        const float* rb = rel + (k0 + 2*j + 1) * 3;
                        float pa = fmaxf(bb + ra[0]*w0 + ra[1]*w1 + ra[2]*w2, 0.f);
                        float pb = fmaxf(bb + rb[0]*w0 + rb[1]*w1 + rb[2]*w2, 0.f);
                        bh.wd[j] = cvtpk(pa, pb);
                    }
                } else {
                    bh.wd[0]=bh.wd[1]=bh.wd[2]=bh.wd[3]=0u;
                }
                acc = __builtin_amdgcn_mfma_f32_16x16x32_bf16(AH[st], bh.v, acc, 0, 0, 0);
                acc = __builtin_amdgcn_mfma_f32_16x16x32_bf16(AL[st], bh.v, acc, 0, 0, 0);
            }
            if (lane < 32) {
                int rb2 = (lane >> 4) * 4;
                #pragma unroll
                for (int j = 0; j < 4; ++j)
                    Pb[(rb2 + j) * 132 + c] = acc[j];
            }
        }
    }
    __syncthreads();

    // ---- phase F: ctx = attn @ Fv (bf16 gather) + Pbar . wv ----
    {
        int c = t & 127, half = t >> 7;
        int h = c >> 4;
        const float* sc = scL + h * 52;
        float accF = 0.f;
        #pragma unroll 4
        for (int kk = 0; kk < 24; ++kk) {
            int k = half * 24 + kk;
            accF += sc[k] * bf2f(FvB[(size_t)idxl[k] * CDIM + c]);
        }
        const float4* wr = (const float4*)(wv + (size_t)c * CDIM) + half * 16;
        const float4* pb4 = (const float4*)(Pb + h * 132) + half * 16;
        #pragma unroll 4
        for (int j = 0; j < 16; ++j) {
            float4 wq = wr[j], p = pb4[j];
            accF += wq.x*p.x + wq.y*p.y + wq.z*p.z + wq.w*p.w;
        }
        pc[half * 128 + c] = accF;
    }
    __syncthreads();
    if (t < CDIM) CTX[n * CDIM + t] = pc[t] + pc[128 + t];
}

// ---------------------------------------------------------------------------
// K3/K6: 128->128 GEMM (bf16 MFMA) + bias (+res f32) + LN (+relu).
// ---------------------------------------------------------------------------
__global__ __launch_bounds__(256) void k_proj_ln_m(
    const float* __restrict__ X, const float* __restrict__ RES,
    const us* __restrict__ WB, const float* __restrict__ B,
    const float* __restrict__ G, const float* __restrict__ LB,
    float* __restrict__ OUT, int N, int relu_out)
{
    __shared__ us xB[16 * 136];
    __shared__ float aL[16][CDIM + 4];
    __shared__ float mu[16], rs[16];
    int row0 = blockIdx.x * 16;
    int t = threadIdx.x;
    {
        int r = t >> 4, cb = (t & 15) * 8;
        int row = row0 + r;
        uint4 o = make_uint4(0, 0, 0, 0);
        if (row < N) {
            float4 v0 = *(const float4*)&X[(size_t)row * CDIM + cb];
            float4 v1 = *(const float4*)&X[(size_t)row * CDIM + cb + 4];
            o.x = cvtpk(v0.x, v0.y); o.y = cvtpk(v0.z, v0.w);
            o.z = cvtpk(v1.x, v1.y); o.w = cvtpk(v1.z, v1.w);
        }
        *(uint4*)&xB[r * 136 + cb] = o;
    }
    __syncthreads();

    int w = t >> 6, lane = t & 63;
    int arow = lane & 15, ko = (lane >> 4) * 8;
    bf16x8 afr[4];
    #pragma unroll
    for (int s = 0; s < 4; ++s)
        afr[s] = *(const bf16x8*)&xB[arow * 136 + s * 32 + ko];

    #pragma unroll
    for (int ct = 0; ct < 2; ++ct) {
        int e0 = (w * 2 + ct) * 16;
        f32x4 acc = {0.f, 0.f, 0.f, 0.f};
        #pragma unroll
        for (int s = 0; s < 4; ++s) {
            bf16x8 bfr = *(const bf16x8*)&WB[(size_t)(e0 + arow) * CDIM + s * 32 + ko];
            acc = __builtin_amdgcn_mfma_f32_16x16x32_bf16(afr[s], bfr, acc, 0, 0, 0);
        }
        int e = e0 + arow;
        float bb = B[e];
        #pragma unroll
        for (int jj = 0; jj < 4; ++jj) {
            int r = (lane >> 4) * 4 + jj;
            int row = row0 + r;
            float a = acc[jj] + bb;
            if (RES != nullptr && row < N) a += RES[(size_t)row * CDIM + e];
            aL[r][e] = a;
        }
    }
    __syncthreads();

    {
        int r = t >> 4, j = t & 15;
        float s = 0.f;
        #pragma unroll
        for (int jj = 0; jj < 8; ++jj) s += aL[r][j * 8 + jj];
        #pragma unroll
        for (int off = 8; off >= 1; off >>= 1) s += __shfl_xor(s, off, 16);
        float mean = s * (1.f / 128.f);
        float v = 0.f;
        #pragma unroll
        for (int jj = 0; jj < 8; ++jj) {
            float d = aL[r][j * 8 + jj] - mean; v += d * d;
        }
        #pragma unroll
        for (int off = 8; off >= 1; off >>= 1) v += __shfl_xor(v, off, 16);
        if (j == 0) { mu[r] = mean; rs[r] = rsqrtf(v * (1.f / 128.f) + 1e-5f); }
    }
    __syncthreads();

    for (int o = t; o < 16 * CDIM; o += 256) {
        int r = o >> 7, c = o & 127;
        int row = row0 + r;
        if (row < N) {
            float y = (aL[r][c] - mu[r]) * rs[r] * G[c] + LB[c];
            if (relu_out) y = fmaxf(y, 0.f);
            OUT[row * CDIM + c] = y;
        }
    }
}

// ---------------------------------------------------------------------------
// K4: ff1 = relu(x @ W1^T + b1) -> HID (bf16), 128 -> 256, bf16 MFMA.
// ---------------------------------------------------------------------------
__global__ __launch_bounds__(256) void k_ff1_m(
    const float* __restrict__ X, const us* __restrict__ WB,
    const float* __restrict__ B, us* __restrict__ HID, int N)
{
    __shared__ us xB[16 * 136];
    int row0 = blockIdx.x * 16;
    int t = threadIdx.x;
    {
        int r = t >> 4, cb = (t & 15) * 8;
        int row = row0 + r;
        uint4 o = make_uint4(0, 0, 0, 0);
        if (row < N) {
            float4 v0 = *(const float4*)&X[(size_t)row * CDIM + cb];
            float4 v1 = *(const float4*)&X[(size_t)row * CDIM + cb + 4];
            o.x = cvtpk(v0.x, v0.y); o.y = cvtpk(v0.z, v0.w);
            o.z = cvtpk(v1.x, v1.y); o.w = cvtpk(v1.z, v1.w);
        }
        *(uint4*)&xB[r * 136 + cb] = o;
    }
    __syncthreads();

    int w = t >> 6, lane = t & 63;
    int arow = lane & 15, ko = (lane >> 4) * 8;
    bf16x8 afr[4];
    #pragma unroll
    for (int s = 0; s < 4; ++s)
        afr[s] = *(const bf16x8*)&xB[arow * 136 + s * 32 + ko];

    #pragma unroll
    for (int ct = 0; ct < 4; ++ct) {
        int e0 = (w * 4 + ct) * 16;
        f32x4 acc = {0.f, 0.f, 0.f, 0.f};
        #pragma unroll
        for (int s = 0; s < 4; ++s) {
            bf16x8 bfr = *(const bf16x8*)&WB[(size_t)(e0 + arow) * CDIM + s * 32 + ko];
            acc = __builtin_amdgcn_mfma_f32_16x16x32_bf16(afr[s], bfr, acc, 0, 0, 0);
        }
        int e = e0 + arow;
        float bb = B[e];
        #pragma unroll
        for (int jj = 0; jj < 4; ++jj) {
            int r = (lane >> 4) * 4 + jj;
            int row = row0 + r;
            if (row < N)
                HID[(size_t)row * FFDIM + e] = f2bf(fmaxf(acc[jj] + bb, 0.f));
        }
    }
}

// ---------------------------------------------------------------------------
// K5: x2 = LN(x1 + hid @ W2^T + b2), 256 -> 128, bf16 MFMA.
// ---------------------------------------------------------------------------
__global__ __launch_bounds__(256) void k_ff2_ln_m(
    const us* __restrict__ HID, const float* __restrict__ RES,
    const us* __restrict__ WB, const float* __restrict__ B,
    const float* __restrict__ G, const float* __restrict__ LB,
    float* __restrict__ OUT, int N)
{
    __shared__ us xB[16 * 264];
    __shared__ float aL[16][CDIM + 4];
    __shared__ float mu[16], rs[16];
    int row0 = blockIdx.x * 16;
    int t = threadIdx.x;
    {
        int r = t >> 4, cb = (t & 15) * 16;
        int row = row0 + r;
        uint4 o0 = make_uint4(0,0,0,0), o1 = make_uint4(0,0,0,0);
        if (row < N) {
            const uint4* hp = (const uint4*)&HID[(size_t)row * FFDIM + cb];
            o0 = hp[0]; o1 = hp[1];
        }
        *(uint4*)&xB[r * 264 + cb] = o0;
        *(uint4*)&xB[r * 264 + cb + 8] = o1;
    }
    __syncthreads();

    int w = t >> 6, lane = t & 63;
    int arow = lane & 15, ko = (lane >> 4) * 8;
    #pragma unroll
    for (int ct = 0; ct < 2; ++ct) {
        int e0 = (w * 2 + ct) * 16;
        f32x4 acc = {0.f, 0.f, 0.f, 0.f};
        #pragma unroll
        for (int s = 0; s < 8; ++s) {
            bf16x8 af = *(const bf16x8*)&xB[arow * 264 + s * 32 + ko];
            bf16x8 bfr = *(const bf16x8*)&WB[(size_t)(e0 + arow) * FFDIM + s * 32 + ko];
            acc = __builtin_amdgcn_mfma_f32_16x16x32_bf16(af, bfr, acc, 0, 0, 0);
        }
        int e = e0 + arow;
        float bb = B[e];
        #pragma unroll
        for (int jj = 0; jj < 4; ++jj) {
            int r = (lane >> 4) * 4 + jj;
            int row = row0 + r;
            float a = acc[jj] + bb;
            if (row < N) a += RES[(size_t)row * CDIM + e];
            aL[r][e] = a;
        }
    }
    __syncthreads();

    {
        int r = t >> 4, j = t & 15;
        float s = 0.f;
        #pragma unroll
        for (int jj = 0; jj < 8; ++jj) s += aL[r][j * 8 + jj];
        #pragma unroll
        for (int off = 8; off >= 1; off >>= 1) s += __shfl_xor(s, off, 16);
        float mean = s * (1.f / 128.f);
        float v = 0.f;
        #pragma unroll
        for (int jj = 0; jj < 8; ++jj) {
            float d = aL[r][j * 8 + jj] - mean; v += d * d;
        }
        #pragma unroll
        for (int off = 8; off >= 1; off >>= 1) v += __shfl_xor(v, off, 16);
        if (j == 0) { mu[r] = mean; rs[r] = rsqrtf(v * (1.f / 128.f) + 1e-5f); }
    }
    __syncthreads();

    for (int o = t; o < 16 * CDIM; o += 256) {
        int r = o >> 7, c = o & 127;
        int row = row0 + r;
        if (row < N)
            OUT[row * CDIM + c] = (aL[r][c] - mu[r]) * rs[r] * G[c] + LB[c];
    }
}

// ---------------------------------------------------------------------------
extern "C" void kernel_launch(void* const* d_in, const int* in_sizes, int n_in,
                              void* d_out, int out_size, void* d_ws, size_t ws_size,
                              hipStream_t stream)
{
    const float* F      = (const float*)d_in[0];
    const float* coords = (const float*)d_in[1];
    const int*   kidx   = (const int*)d_in[2];
    const void*  kmask  = d_in[3];
    const float* ipw    = (const float*)d_in[4];
    const float* ipb    = (const float*)d_in[5];
    const float* opw    = (const float*)d_in[6];
    const float* opb    = (const float*)d_in[7];
    const float* kpw    = (const float*)d_in[8];
    const float* kpb    = (const float*)d_in[9];
    const float* ln1g   = (const float*)d_in[10];
    const float* ln1b   = (const float*)d_in[11];
    const float* ln2g   = (const float*)d_in[12];
    const float* ln2b   = (const float*)d_in[13];
    const float* w1     = (const float*)d_in[14];
    const float* b1     = (const float*)d_in[15];
    const float* w2     = (const float*)d_in[16];
    const float* b2     = (const float*)d_in[17];
    const float* ow     = (const float*)d_in[18];
    const float* ob     = (const float*)d_in[19];
    const float* ln3g   = (const float*)d_in[20];
    const float* ln3b   = (const float*)d_in[21];

    int N = in_sizes[0] / CDIM;
    size_t NC = (size_t)N * CDIM;

    float* ws  = (float*)d_ws;
    float* Q    = ws;
    us*    FkB  = (us*)(ws + NC);
    us*    FvB  = (us*)(ws + NC) + NC;
    float* CTX  = ws + 2 * NC;
    float* X1   = Q;
    us*    HID  = (us*)(ws + NC);
    float* X2   = ws + 3 * NC;
    float* WTq  = ws + 4 * NC;
    us*    WBo  = (us*)(WTq + 384 * 128);
    us*    WB1  = WBo + 128 * 128;
    us*    WB2  = WB1 + 256 * 128;
    us*    WBw  = WB2 + 128 * 256;
    int*   mflag = (int*)(WBw + 128 * 128);

    const float* wk = ipw + CDIM * CDIM;
    const float* wv = ipw + 2 * CDIM * CDIM;

    hipMemsetAsync(mflag, 0, sizeof(int), stream);
    int nwords = (N * KNBR) / 4;
    k_mask_probe<<<256, 256, 0, stream>>>((const u32*)kmask, nwords, mflag);

    k_wt<<<(384 * 32 + 255) / 256, 256, 0, stream>>>(ipw, WTq, 384, 32);
    k_wb<<<(128 * 64 + 255) / 256, 256, 0, stream>>>(opw, WBo, 128 * 64);
    k_wb<<<(256 * 64 + 255) / 256, 256, 0, stream>>>(w1,  WB1, 256 * 64);
    k_wb<<<(128 * 128 + 255) / 256, 256, 0, stream>>>(w2, WB2, 128 * 128);
    k_wb<<<(128 * 64 + 255) / 256, 256, 0, stream>>>(ow,  WBw, 128 * 64);

    k_qkv<<<(N + 7) / 8, 384, 0, stream>>>(F, WTq, ipb, Q, FkB, FvB, N);
    k_attn<<<N, 256, 0, stream>>>(coords, kidx, (const u8*)kmask,
                                  (const int*)kmask, mflag, Q, FkB, FvB,
                                  wk, wv, kpw, kpb, CTX);
    k_proj_ln_m<<<(N + 15) / 16, 256, 0, stream>>>(CTX, F, WBo, opb,
                                                   ln1g, ln1b, X1, N, 0);
    k_ff1_m<<<(N + 15) / 16, 256, 0, stream>>>(X1, WB1, b1, HID, N);
    k_ff2_ln_m<<<(N + 15) / 16, 256, 0, stream>>>(HID, X1, WB2, b2,
                                                  ln2g, ln2b, X2, N);
    k_proj_ln_m<<<(N + 15) / 16, 256, 0, stream>>>(X2, nullptr, WBw, ob,
                                                   ln3g, ln3b, (float*)d_out, N, 1);
}

// Round 14
// 776.999 us; speedup vs baseline: 1.6472x; 1.0710x over previous
//
#include <hip/hip_runtime.h>
#include <stdint.h>

typedef unsigned char u8;
typedef unsigned short us;
typedef unsigned int u32;

#define CDIM  128
#define KNBR  48
#define HEADS 8
#define DHEAD 16
#define FFDIM 256

using bf16x8 = __attribute__((ext_vector_type(8))) short;  // 8 bf16 (4 VGPRs)
using f32x4  = __attribute__((ext_vector_type(4))) float;  // 4 fp32

__device__ inline float blo32(u32 u) { union { u32 i; float f; } v; v.i = u << 16; return v.f; }
__device__ inline float bhi32(u32 u) { union { u32 i; float f; } v; v.i = u & 0xFFFF0000u; return v.f; }
__device__ inline float bf2f(us u) { union { u32 i; float f; } v; v.i = ((u32)u) << 16; return v.f; }
__device__ inline us f2bf(float x) {
    union { float f; u32 i; } v; v.f = x;
    u32 r = v.i + 0x7FFFu + ((v.i >> 16) & 1u);
    return (us)(r >> 16);
}
// HW packed f32x2 -> bf16x2 (RNE), one instruction (gfx950; no builtin).
__device__ inline u32 cvtpk(float a, float b) {
    u32 r;
    asm("v_cvt_pk_bf16_f32 %0, %1, %2" : "=v"(r) : "v"(a), "v"(b));
    return r;
}

// ---------------------------------------------------------------------------
// K0: probe key_mask storage (int32 vs u8 bool). flag=1 -> u8 storage.
// ---------------------------------------------------------------------------
__global__ void k_mask_probe(const u32* __restrict__ mw, int nwords,
                             int* __restrict__ flag)
{
    u32 any = 0;
    for (int j = blockIdx.x * blockDim.x + threadIdx.x; j < nwords;
         j += gridDim.x * blockDim.x)
        any |= mw[j] & 0xFFFFFF00u;
    if (any) atomicOr(flag, 1);
}

// ---------------------------------------------------------------------------
// K0c: f32 W -> bf16 row-major. n2 = elems/2.
// ---------------------------------------------------------------------------
__global__ __launch_bounds__(256) void k_wb(
    const float* __restrict__ W, us* __restrict__ WB, int n2)
{
    int i = blockIdx.x * 256 + threadIdx.x;
    if (i < n2) {
        float2 v = *(const float2*)(W + (size_t)i * 2);
        ((u32*)WB)[i] = cvtpk(v.x, v.y);
    }
}

// ---------------------------------------------------------------------------
// K0d: f32 W -> hi + lo bf16 planes (f32-grade when used with 3-term MFMA).
// ---------------------------------------------------------------------------
__global__ __launch_bounds__(256) void k_wb_hl(
    const float* __restrict__ W, us* __restrict__ WH, us* __restrict__ WL,
    int n2)
{
    int i = blockIdx.x * 256 + threadIdx.x;
    if (i < n2) {
        float2 v = *(const float2*)(W + (size_t)i * 2);
        u32 h = cvtpk(v.x, v.y);
        ((u32*)WH)[i] = h;
        ((u32*)WL)[i] = cvtpk(v.x - blo32(h), v.y - bhi32(h));
    }
}

// ---------------------------------------------------------------------------
// K1: QKV projection via MFMA. x staged as hi/lo bf16. Q cols (tiles 0-7):
// 3-term hi/lo MFMA (f32-grade, q feeds the O(100) score path). Fk/Fv cols
// (tiles 8-23): 2-term (= f32-x . bf16-W; outputs are bf16-stored anyway).
// 16 rows/block, 4 waves; tile = w + 4*i interleaves Q-tiles across waves.
// ---------------------------------------------------------------------------
__global__ __launch_bounds__(256) void k_qkv_m(
    const float* __restrict__ F,
    const us* __restrict__ WQh, const us* __restrict__ WQl,
    const us* __restrict__ WKV, const float* __restrict__ B,
    float* __restrict__ Q, us* __restrict__ FkB, us* __restrict__ FvB, int N)
{
    __shared__ us xH[16 * 136];
    __shared__ us xLo[16 * 136];
    int row0 = blockIdx.x * 16;
    int t = threadIdx.x;
    {
        int r = t >> 4, cb = (t & 15) * 8;
        int row = row0 + r;
        uint4 oh = make_uint4(0,0,0,0), ol = make_uint4(0,0,0,0);
        if (row < N) {
            float4 v0 = *(const float4*)&F[(size_t)row * CDIM + cb];
            float4 v1 = *(const float4*)&F[(size_t)row * CDIM + cb + 4];
            oh.x = cvtpk(v0.x, v0.y); oh.y = cvtpk(v0.z, v0.w);
            oh.z = cvtpk(v1.x, v1.y); oh.w = cvtpk(v1.z, v1.w);
            ol.x = cvtpk(v0.x - blo32(oh.x), v0.y - bhi32(oh.x));
            ol.y = cvtpk(v0.z - blo32(oh.y), v0.w - bhi32(oh.y));
            ol.z = cvtpk(v1.x - blo32(oh.z), v1.y - bhi32(oh.z));
            ol.w = cvtpk(v1.z - blo32(oh.w), v1.w - bhi32(oh.w));
        }
        *(uint4*)&xH[r * 136 + cb] = oh;
        *(uint4*)&xLo[r * 136 + cb] = ol;
    }
    __syncthreads();

    int w = t >> 6, lane = t & 63;
    int arow = lane & 15, ko = (lane >> 4) * 8;
    bf16x8 ah[4], al[4];
    #pragma unroll
    for (int s = 0; s < 4; ++s) {
        ah[s] = *(const bf16x8*)&xH[arow * 136 + s * 32 + ko];
        al[s] = *(const bf16x8*)&xLo[arow * 136 + s * 32 + ko];
    }

    #pragma unroll
    for (int i = 0; i < 6; ++i) {
        int tile = w + 4 * i;               // 0..23, Q-tiles spread over waves
        int e0 = tile * 16;
        f32x4 acc = {0.f, 0.f, 0.f, 0.f};
        if (tile < 8) {
            const us* wh = WQh + (size_t)(e0 + arow) * CDIM;
            const us* wl = WQl + (size_t)(e0 + arow) * CDIM;
            #pragma unroll
            for (int s = 0; s < 4; ++s) {
                bf16x8 bh = *(const bf16x8*)(wh + s * 32 + ko);
                bf16x8 bl = *(const bf16x8*)(wl + s * 32 + ko);
                acc = __builtin_amdgcn_mfma_f32_16x16x32_bf16(ah[s], bh, acc, 0, 0, 0);
                acc = __builtin_amdgcn_mfma_f32_16x16x32_bf16(ah[s], bl, acc, 0, 0, 0);
                acc = __builtin_amdgcn_mfma_f32_16x16x32_bf16(al[s], bh, acc, 0, 0, 0);
            }
        } else {
            const us* wp = WKV + (size_t)(e0 - 128 + arow) * CDIM;
            #pragma unroll
            for (int s = 0; s < 4; ++s) {
                bf16x8 bh = *(const bf16x8*)(wp + s * 32 + ko);
                acc = __builtin_amdgcn_mfma_f32_16x16x32_bf16(ah[s], bh, acc, 0, 0, 0);
                acc = __builtin_amdgcn_mfma_f32_16x16x32_bf16(al[s], bh, acc, 0, 0, 0);
            }
        }
        int e = e0 + arow;
        float bb = B[e];
        #pragma unroll
        for (int jj = 0; jj < 4; ++jj) {
            int r = (lane >> 4) * 4 + jj;
            int row = row0 + r;
            if (row >= N) continue;
            float a = acc[jj] + bb;
            if (e < 128)       Q[(size_t)row * CDIM + e] = a;
            else if (e < 256)  FkB[(size_t)row * CDIM + (e - 128)] = f2bf(a);
            else               FvB[(size_t)row * CDIM + (e - 256)] = f2bf(a);
        }
    }
}

// ---------------------------------------------------------------------------
// K2: attention (R13-verbatim: 657 us, occupancy 79%, no spill).
// ---------------------------------------------------------------------------
__global__ __launch_bounds__(256, 6) void k_attn(
    const float* __restrict__ coords, const int* __restrict__ kidx,
    const u8* __restrict__ kmask_u8, const int* __restrict__ kmask_i32,
    const int* __restrict__ maskflag,
    const float* __restrict__ Q, const us* __restrict__ FkB,
    const us* __restrict__ FvB,
    const float* __restrict__ wk, const float* __restrict__ wv,
    const float* __restrict__ kpw, const float* __restrict__ kpb,
    float* __restrict__ CTX)
{
    __shared__ __align__(16) u8 SM[14656];
    us*    qwH   = (us*)(SM);
    us*    qwL   = (us*)(SM + 2176);
    float* scL   = (float*)(SM + 4352);
    float* Ql    = (float*)(SM + 6016);
    float* rel   = (float*)(SM + 6528);
    float* kpw0S = (float*)(SM + 7104);
    float* kpw1S = (float*)(SM + 7616);
    float* kpw2S = (float*)(SM + 8128);
    float* kpbS  = (float*)(SM + 8640);
    int*   idxl  = (int*)  (SM + 9152);
    u8*    mskl  = (u8*)   (SM + 9344);
    float* Pb    = (float*)(SM + 9408);
    float* pc    = (float*)(SM + 13632);

    int n = blockIdx.x;
    int t = threadIdx.x;
    int w = t >> 6, lane = t & 63;

    if (t < KNBR) {
        int idx = kidx[n * KNBR + t];
        idxl[t] = idx;
        mskl[t] = maskflag[0] ? kmask_u8[n * KNBR + t]
                              : (u8)kmask_i32[n * KNBR + t];
        rel[t * 3 + 0] = coords[idx * 3 + 0] - coords[n * 3 + 0];
        rel[t * 3 + 1] = coords[idx * 3 + 1] - coords[n * 3 + 1];
        rel[t * 3 + 2] = coords[idx * 3 + 2] - coords[n * 3 + 2];
    }
    if (t < 128) {
        kpw0S[t] = kpw[t * 3 + 0];
        kpw1S[t] = kpw[t * 3 + 1];
        kpw2S[t] = kpw[t * 3 + 2];
        kpbS[t]  = kpb[t];
    } else {
        Ql[t - 128] = Q[n * CDIM + (t - 128)];
    }
    __syncthreads();

    {
        int h = t >> 5, c4 = t & 31;
        const float* qh = Ql + h * DHEAD;
        float a0=0.f, a1=0.f, a2=0.f, a3=0.f;
        #pragma unroll
        for (int d = 0; d < DHEAD; ++d) {
            float q = qh[d];
            float4 wr = *(const float4*)(wk + (size_t)(h * DHEAD + d) * CDIM + c4 * 4);
            a0 += q * wr.x; a1 += q * wr.y; a2 += q * wr.z; a3 += q * wr.w;
        }
        uint2 ph, pl;
        ph.x = cvtpk(a0, a1);
        ph.y = cvtpk(a2, a3);
        pl.x = cvtpk(a0 - blo32(ph.x), a1 - bhi32(ph.x));
        pl.y = cvtpk(a2 - blo32(ph.y), a3 - bhi32(ph.y));
        *(uint2*)&qwH[h * 136 + c4 * 4] = ph;
        *(uint2*)&qwL[h * 136 + c4 * 4] = pl;
    }

    if (w == 3) {
        #pragma unroll
        for (int i = 0; i < 6; ++i) {
            int o = lane * 6 + i;
            int k = o >> 3, h = o & 7;
            const float* qh = Ql + h * DHEAD;
            const uint4* fk = (const uint4*)(FkB + (size_t)idxl[k] * CDIM + h * DHEAD);
            uint4 fa = fk[0], fb = fk[1];
            float s = qh[0]*blo32(fa.x) + qh[1]*bhi32(fa.x)
                    + qh[2]*blo32(fa.y) + qh[3]*bhi32(fa.y)
                    + qh[4]*blo32(fa.z) + qh[5]*bhi32(fa.z)
                    + qh[6]*blo32(fa.w) + qh[7]*bhi32(fa.w)
                    + qh[8]*blo32(fb.x) + qh[9]*bhi32(fb.x)
                    + qh[10]*blo32(fb.y) + qh[11]*bhi32(fb.y)
                    + qh[12]*blo32(fb.z) + qh[13]*bhi32(fb.z)
                    + qh[14]*blo32(fb.w) + qh[15]*bhi32(fb.w);
            scL[h * 52 + k] = s;
        }
    }
    __syncthreads();

    union U8 { bf16x8 v; u32 wd[4]; };

    if (w < 3) {
        f32x4 acc = {0.f, 0.f, 0.f, 0.f};
        int kk = w * 16 + (lane & 15);
        int cb0 = (lane >> 4) * 8;
        int arow = lane & 15;
        bool aval = arow < 8;
        bf16x8 zz = {0,0,0,0,0,0,0,0};
        float r0 = rel[kk * 3], r1 = rel[kk * 3 + 1], r2 = rel[kk * 3 + 2];
        #pragma unroll
        for (int s = 0; s < 4; ++s) {
            int cb = cb0 + s * 32;
            float4 x0 = *(const float4*)&kpw0S[cb], x1 = *(const float4*)&kpw0S[cb + 4];
            float4 y0 = *(const float4*)&kpw1S[cb], y1 = *(const float4*)&kpw1S[cb + 4];
            float4 z0 = *(const float4*)&kpw2S[cb], z1 = *(const float4*)&kpw2S[cb + 4];
            float4 b0 = *(const float4*)&kpbS[cb],  b1 = *(const float4*)&kpbS[cb + 4];
            float p[8];
            p[0] = fmaxf(b0.x + r0*x0.x + r1*y0.x + r2*z0.x, 0.f);
            p[1] = fmaxf(b0.y + r0*x0.y + r1*y0.y + r2*z0.y, 0.f);
            p[2] = fmaxf(b0.z + r0*x0.z + r1*y0.z + r2*z0.z, 0.f);
            p[3] = fmaxf(b0.w + r0*x0.w + r1*y0.w + r2*z0.w, 0.f);
            p[4] = fmaxf(b1.x + r0*x1.x + r1*y1.x + r2*z1.x, 0.f);
            p[5] = fmaxf(b1.y + r0*x1.y + r1*y1.y + r2*z1.y, 0.f);
            p[6] = fmaxf(b1.z + r0*x1.z + r1*y1.z + r2*z1.z, 0.f);
            p[7] = fmaxf(b1.w + r0*x1.w + r1*y1.w + r2*z1.w, 0.f);
            U8 bh, bl;
            #pragma unroll
            for (int j = 0; j < 4; ++j) {
                u32 hh = cvtpk(p[2*j], p[2*j+1]);
                bh.wd[j] = hh;
                bl.wd[j] = cvtpk(p[2*j] - blo32(hh), p[2*j+1] - bhi32(hh));
            }
            int c0 = s * 32 + cb0;
            bf16x8 ahf = aval ? *(const bf16x8*)(qwH + arow * 136 + c0) : zz;
            bf16x8 alf = aval ? *(const bf16x8*)(qwL + arow * 136 + c0) : zz;
            acc = __builtin_amdgcn_mfma_f32_16x16x32_bf16(ahf, bh.v, acc, 0, 0, 0);
            acc = __builtin_amdgcn_mfma_f32_16x16x32_bf16(ahf, bl.v, acc, 0, 0, 0);
            acc = __builtin_amdgcn_mfma_f32_16x16x32_bf16(alf, bh.v, acc, 0, 0, 0);
        }
        if (lane < 32) {
            int kc = w * 16 + (lane & 15);
            int rb = (lane >> 4) * 4;
            u8 mk = mskl[kc];
            #pragma unroll
            for (int j = 0; j < 4; ++j) {
                int h = rb + j;
                float s = acc[j] + scL[h * 52 + kc];
                scL[h * 52 + kc] = mk ? -1e30f : s * 0.25f;
            }
        }
    }
    __syncthreads();

    {
        int h = t >> 5, l32 = t & 31;
        float* sc = scL + h * 52;
        float v0 = sc[l32];
        float v1 = (l32 < KNBR - 32) ? sc[l32 + 32] : -1e30f;
        float m = fmaxf(v0, v1);
        #pragma unroll
        for (int off = 16; off >= 1; off >>= 1)
            m = fmaxf(m, __shfl_xor(m, off, 32));
        float e0 = __expf(v0 - m);
        float e1 = (l32 < KNBR - 32) ? __expf(v1 - m) : 0.f;
        float s = e0 + e1;
        #pragma unroll
        for (int off = 16; off >= 1; off >>= 1)
            s += __shfl_xor(s, off, 32);
        float inv = 1.f / s;
        sc[l32] = e0 * inv;
        if (l32 < KNBR - 32) sc[l32 + 32] = e1 * inv;
    }
    __syncthreads();

    {
        bf16x8 AH[2], AL[2];
        int arow = lane & 15;
        bool av = arow < 8;
        #pragma unroll
        for (int st = 0; st < 2; ++st) {
            int k0 = (lane >> 4) * 8 + st * 32;
            float pr[8];
            if (av && k0 < KNBR) {
                float4 s0 = *(const float4*)&scL[arow * 52 + k0];
                float4 s1 = *(const float4*)&scL[arow * 52 + k0 + 4];
                pr[0]=s0.x; pr[1]=s0.y; pr[2]=s0.z; pr[3]=s0.w;
                pr[4]=s1.x; pr[5]=s1.y; pr[6]=s1.z; pr[7]=s1.w;
            } else {
                #pragma unroll
                for (int j = 0; j < 8; ++j) pr[j] = 0.f;
            }
            U8 ah, al;
            #pragma unroll
            for (int j = 0; j < 4; ++j) {
                u32 hh = cvtpk(pr[2*j], pr[2*j+1]);
                ah.wd[j] = hh;
                al.wd[j] = cvtpk(pr[2*j] - blo32(hh), pr[2*j+1] - bhi32(hh));
            }
            AH[st] = ah.v; AL[st] = al.v;
        }
        #pragma unroll
        for (int ct = 0; ct < 2; ++ct) {
            int c = w * 32 + ct * 16 + (lane & 15);
            float w0 = kpw0S[c], w1 = kpw1S[c], w2 = kpw2S[c], bb = kpbS[c];
            f32x4 acc = {0.f, 0.f, 0.f, 0.f};
            #pragma unroll
            for (int st = 0; st < 2; ++st) {
                int k0 = (lane >> 4) * 8 + st * 32;
                U8 bh;
                if (k0 < KNBR) {
                    #pragma unroll
                    for (int j = 0; j < 4; ++j) {
                        const float* ra = rel + (k0 + 2*j) * 3;
                        const float* rb = rel + (k0 + 2*j + 1) * 3;
                        float pa = fmaxf(bb + ra[0]*w0 + ra[1]*w1 + ra[2]*w2, 0.f);
                        float pb = fmaxf(bb + rb[0]*w0 + rb[1]*w1 + rb[2]*w2, 0.f);
                        bh.wd[j] = cvtpk(pa, pb);
                    }
                } else {
                    bh.wd[0]=bh.wd[1]=bh.wd[2]=bh.wd[3]=0u;
                }
                acc = __builtin_amdgcn_mfma_f32_16x16x32_bf16(AH[st], bh.v, acc, 0, 0, 0);
                acc = __builtin_amdgcn_mfma_f32_16x16x32_bf16(AL[st], bh.v, acc, 0, 0, 0);
            }
            if (lane < 32) {
                int rb2 = (lane >> 4) * 4;
                #pragma unroll
                for (int j = 0; j < 4; ++j)
                    Pb[(rb2 + j) * 132 + c] = acc[j];
            }
        }
    }
    __syncthreads();

    {
        int c = t & 127, half = t >> 7;
        int h = c >> 4;
        const float* sc = scL + h * 52;
        float accF = 0.f;
        #pragma unroll 4
        for (int kk = 0; kk < 24; ++kk) {
            int k = half * 24 + kk;
            accF += sc[k] * bf2f(FvB[(size_t)idxl[k] * CDIM + c]);
        }
        const float4* wr = (const float4*)(wv + (size_t)c * CDIM) + half * 16;
        const float4* pb4 = (const float4*)(Pb + h * 132) + half * 16;
        #pragma unroll 4
        for (int j = 0; j < 16; ++j) {
            float4 wq = wr[j], p = pb4[j];
            accF += wq.x*p.x + wq.y*p.y + wq.z*p.z + wq.w*p.w;
        }
        pc[half * 128 + c] = accF;
    }
    __syncthreads();
    if (t < CDIM) CTX[n * CDIM + t] = pc[t] + pc[128 + t];
}

// ---------------------------------------------------------------------------
// K3/K6: 128->128 GEMM (bf16 MFMA) + bias (+res f32) + LN (+relu).
// ---------------------------------------------------------------------------
__global__ __launch_bounds__(256) void k_proj_ln_m(
    const float* __restrict__ X, const float* __restrict__ RES,
    const us* __restrict__ WB, const float* __restrict__ B,
    const float* __restrict__ G, const float* __restrict__ LB,
    float* __restrict__ OUT, int N, int relu_out)
{
    __shared__ us xB[16 * 136];
    __shared__ float aL[16][CDIM + 4];
    __shared__ float mu[16], rs[16];
    int row0 = blockIdx.x * 16;
    int t = threadIdx.x;
    {
        int r = t >> 4, cb = (t & 15) * 8;
        int row = row0 + r;
        uint4 o = make_uint4(0, 0, 0, 0);
        if (row < N) {
            float4 v0 = *(const float4*)&X[(size_t)row * CDIM + cb];
            float4 v1 = *(const float4*)&X[(size_t)row * CDIM + cb + 4];
            o.x = cvtpk(v0.x, v0.y); o.y = cvtpk(v0.z, v0.w);
            o.z = cvtpk(v1.x, v1.y); o.w = cvtpk(v1.z, v1.w);
        }
        *(uint4*)&xB[r * 136 + cb] = o;
    }
    __syncthreads();

    int w = t >> 6, lane = t & 63;
    int arow = lane & 15, ko = (lane >> 4) * 8;
    bf16x8 afr[4];
    #pragma unroll
    for (int s = 0; s < 4; ++s)
        afr[s] = *(const bf16x8*)&xB[arow * 136 + s * 32 + ko];

    #pragma unroll
    for (int ct = 0; ct < 2; ++ct) {
        int e0 = (w * 2 + ct) * 16;
        f32x4 acc = {0.f, 0.f, 0.f, 0.f};
        #pragma unroll
        for (int s = 0; s < 4; ++s) {
            bf16x8 bfr = *(const bf16x8*)&WB[(size_t)(e0 + arow) * CDIM + s * 32 + ko];
            acc = __builtin_amdgcn_mfma_f32_16x16x32_bf16(afr[s], bfr, acc, 0, 0, 0);
        }
        int e = e0 + arow;
        float bb = B[e];
        #pragma unroll
        for (int jj = 0; jj < 4; ++jj) {
            int r = (lane >> 4) * 4 + jj;
            int row = row0 + r;
            float a = acc[jj] + bb;
            if (RES != nullptr && row < N) a += RES[(size_t)row * CDIM + e];
            aL[r][e] = a;
        }
    }
    __syncthreads();

    {
        int r = t >> 4, j = t & 15;
        float s = 0.f;
        #pragma unroll
        for (int jj = 0; jj < 8; ++jj) s += aL[r][j * 8 + jj];
        #pragma unroll
        for (int off = 8; off >= 1; off >>= 1) s += __shfl_xor(s, off, 16);
        float mean = s * (1.f / 128.f);
        float v = 0.f;
        #pragma unroll
        for (int jj = 0; jj < 8; ++jj) {
            float d = aL[r][j * 8 + jj] - mean; v += d * d;
        }
        #pragma unroll
        for (int off = 8; off >= 1; off >>= 1) v += __shfl_xor(v, off, 16);
        if (j == 0) { mu[r] = mean; rs[r] = rsqrtf(v * (1.f / 128.f) + 1e-5f); }
    }
    __syncthreads();

    for (int o = t; o < 16 * CDIM; o += 256) {
        int r = o >> 7, c = o & 127;
        int row = row0 + r;
        if (row < N) {
            float y = (aL[r][c] - mu[r]) * rs[r] * G[c] + LB[c];
            if (relu_out) y = fmaxf(y, 0.f);
            OUT[row * CDIM + c] = y;
        }
    }
}

// ---------------------------------------------------------------------------
// K4: ff1 = relu(x @ W1^T + b1) -> HID (bf16), 128 -> 256, bf16 MFMA.
// ---------------------------------------------------------------------------
__global__ __launch_bounds__(256) void k_ff1_m(
    const float* __restrict__ X, const us* __restrict__ WB,
    const float* __restrict__ B, us* __restrict__ HID, int N)
{
    __shared__ us xB[16 * 136];
    int row0 = blockIdx.x * 16;
    int t = threadIdx.x;
    {
        int r = t >> 4, cb = (t & 15) * 8;
        int row = row0 + r;
        uint4 o = make_uint4(0, 0, 0, 0);
        if (row < N) {
            float4 v0 = *(const float4*)&X[(size_t)row * CDIM + cb];
            float4 v1 = *(const float4*)&X[(size_t)row * CDIM + cb + 4];
            o.x = cvtpk(v0.x, v0.y); o.y = cvtpk(v0.z, v0.w);
            o.z = cvtpk(v1.x, v1.y); o.w = cvtpk(v1.z, v1.w);
        }
        *(uint4*)&xB[r * 136 + cb] = o;
    }
    __syncthreads();

    int w = t >> 6, lane = t & 63;
    int arow = lane & 15, ko = (lane >> 4) * 8;
    bf16x8 afr[4];
    #pragma unroll
    for (int s = 0; s < 4; ++s)
        afr[s] = *(const bf16x8*)&xB[arow * 136 + s * 32 + ko];

    #pragma unroll
    for (int ct = 0; ct < 4; ++ct) {
        int e0 = (w * 4 + ct) * 16;
        f32x4 acc = {0.f, 0.f, 0.f, 0.f};
        #pragma unroll
        for (int s = 0; s < 4; ++s) {
            bf16x8 bfr = *(const bf16x8*)&WB[(size_t)(e0 + arow) * CDIM + s * 32 + ko];
            acc = __builtin_amdgcn_mfma_f32_16x16x32_bf16(afr[s], bfr, acc, 0, 0, 0);
        }
        int e = e0 + arow;
        float bb = B[e];
        #pragma unroll
        for (int jj = 0; jj < 4; ++jj) {
            int r = (lane >> 4) * 4 + jj;
            int row = row0 + r;
            if (row < N)
                HID[(size_t)row * FFDIM + e] = f2bf(fmaxf(acc[jj] + bb, 0.f));
        }
    }
}

// ---------------------------------------------------------------------------
// K5: x2 = LN(x1 + hid @ W2^T + b2), 256 -> 128, bf16 MFMA.
// ---------------------------------------------------------------------------
__global__ __launch_bounds__(256) void k_ff2_ln_m(
    const us* __restrict__ HID, const float* __restrict__ RES,
    const us* __restrict__ WB, const float* __restrict__ B,
    const float* __restrict__ G, const float* __restrict__ LB,
    float* __restrict__ OUT, int N)
{
    __shared__ us xB[16 * 264];
    __shared__ float aL[16][CDIM + 4];
    __shared__ float mu[16], rs[16];
    int row0 = blockIdx.x * 16;
    int t = threadIdx.x;
    {
        int r = t >> 4, cb = (t & 15) * 16;
        int row = row0 + r;
        uint4 o0 = make_uint4(0,0,0,0), o1 = make_uint4(0,0,0,0);
        if (row < N) {
            const uint4* hp = (const uint4*)&HID[(size_t)row * FFDIM + cb];
            o0 = hp[0]; o1 = hp[1];
        }
        *(uint4*)&xB[r * 264 + cb] = o0;
        *(uint4*)&xB[r * 264 + cb + 8] = o1;
    }
    __syncthreads();

    int w = t >> 6, lane = t & 63;
    int arow = lane & 15, ko = (lane >> 4) * 8;
    #pragma unroll
    for (int ct = 0; ct < 2; ++ct) {
        int e0 = (w * 2 + ct) * 16;
        f32x4 acc = {0.f, 0.f, 0.f, 0.f};
        #pragma unroll
        for (int s = 0; s < 8; ++s) {
            bf16x8 af = *(const bf16x8*)&xB[arow * 264 + s * 32 + ko];
            bf16x8 bfr = *(const bf16x8*)&WB[(size_t)(e0 + arow) * FFDIM + s * 32 + ko];
            acc = __builtin_amdgcn_mfma_f32_16x16x32_bf16(af, bfr, acc, 0, 0, 0);
        }
        int e = e0 + arow;
        float bb = B[e];
        #pragma unroll
        for (int jj = 0; jj < 4; ++jj) {
            int r = (lane >> 4) * 4 + jj;
            int row = row0 + r;
            float a = acc[jj] + bb;
            if (row < N) a += RES[(size_t)row * CDIM + e];
            aL[r][e] = a;
        }
    }
    __syncthreads();

    {
        int r = t >> 4, j = t & 15;
        float s = 0.f;
        #pragma unroll
        for (int jj = 0; jj < 8; ++jj) s += aL[r][j * 8 + jj];
        #pragma unroll
        for (int off = 8; off >= 1; off >>= 1) s += __shfl_xor(s, off, 16);
        float mean = s * (1.f / 128.f);
        float v = 0.f;
        #pragma unroll
        for (int jj = 0; jj < 8; ++jj) {
            float d = aL[r][j * 8 + jj] - mean; v += d * d;
        }
        #pragma unroll
        for (int off = 8; off >= 1; off >>= 1) v += __shfl_xor(v, off, 16);
        if (j == 0) { mu[r] = mean; rs[r] = rsqrtf(v * (1.f / 128.f) + 1e-5f); }
    }
    __syncthreads();

    for (int o = t; o < 16 * CDIM; o += 256) {
        int r = o >> 7, c = o & 127;
        int row = row0 + r;
        if (row < N)
            OUT[row * CDIM + c] = (aL[r][c] - mu[r]) * rs[r] * G[c] + LB[c];
    }
}

// ---------------------------------------------------------------------------
extern "C" void kernel_launch(void* const* d_in, const int* in_sizes, int n_in,
                              void* d_out, int out_size, void* d_ws, size_t ws_size,
                              hipStream_t stream)
{
    const float* F      = (const float*)d_in[0];
    const float* coords = (const float*)d_in[1];
    const int*   kidx   = (const int*)d_in[2];
    const void*  kmask  = d_in[3];
    const float* ipw    = (const float*)d_in[4];
    const float* ipb    = (const float*)d_in[5];
    const float* opw    = (const float*)d_in[6];
    const float* opb    = (const float*)d_in[7];
    const float* kpw    = (const float*)d_in[8];
    const float* kpb    = (const float*)d_in[9];
    const float* ln1g   = (const float*)d_in[10];
    const float* ln1b   = (const float*)d_in[11];
    const float* ln2g   = (const float*)d_in[12];
    const float* ln2b   = (const float*)d_in[13];
    const float* w1     = (const float*)d_in[14];
    const float* b1     = (const float*)d_in[15];
    const float* w2     = (const float*)d_in[16];
    const float* b2     = (const float*)d_in[17];
    const float* ow     = (const float*)d_in[18];
    const float* ob     = (const float*)d_in[19];
    const float* ln3g   = (const float*)d_in[20];
    const float* ln3b   = (const float*)d_in[21];

    int N = in_sizes[0] / CDIM;
    size_t NC = (size_t)N * CDIM;

    float* ws  = (float*)d_ws;
    // layout (floats):
    //   [0,   NC)    Q  (later X1)
    //   [NC,  1.5NC) FkB (bf16)  } HID (bf16, N*256 us) = [NC,2NC) after attn
    //   [1.5NC,2NC)  FvB (bf16)  }
    //   [2NC, 3NC)   CTX
    //   [3NC, 4NC)   X2
    //   [4NC, ...)   WQh,WQl(128*128 us each) WKV(256*128) WBo,WB1,WB2,WBw | mflag
    float* Q    = ws;
    us*    FkB  = (us*)(ws + NC);
    us*    FvB  = (us*)(ws + NC) + NC;
    float* CTX  = ws + 2 * NC;
    float* X1   = Q;
    us*    HID  = (us*)(ws + NC);
    float* X2   = ws + 3 * NC;
    us*    WQh  = (us*)(ws + 4 * NC);       // 128*128
    us*    WQl  = WQh + 128 * 128;          // 128*128
    us*    WKV  = WQl + 128 * 128;          // 256*128
    us*    WBo  = WKV + 256 * 128;          // 128*128
    us*    WB1  = WBo + 128 * 128;          // 256*128
    us*    WB2  = WB1 + 256 * 128;          // 128*256
    us*    WBw  = WB2 + 128 * 256;          // 128*128
    int*   mflag = (int*)(WBw + 128 * 128);

    const float* wk = ipw + CDIM * CDIM;
    const float* wv = ipw + 2 * CDIM * CDIM;

    hipMemsetAsync(mflag, 0, sizeof(int), stream);
    int nwords = (N * KNBR) / 4;
    k_mask_probe<<<256, 256, 0, stream>>>((const u32*)kmask, nwords, mflag);

    // one-time weight prep
    k_wb_hl<<<(128 * 64 + 255) / 256, 256, 0, stream>>>(ipw, WQh, WQl, 128 * 64);
    k_wb<<<(256 * 64 + 255) / 256, 256, 0, stream>>>(ipw + 128 * CDIM, WKV, 256 * 64);
    k_wb<<<(128 * 64 + 255) / 256, 256, 0, stream>>>(opw, WBo, 128 * 64);
    k_wb<<<(256 * 64 + 255) / 256, 256, 0, stream>>>(w1,  WB1, 256 * 64);
    k_wb<<<(128 * 128 + 255) / 256, 256, 0, stream>>>(w2, WB2, 128 * 128);
    k_wb<<<(128 * 64 + 255) / 256, 256, 0, stream>>>(ow,  WBw, 128 * 64);

    k_qkv_m<<<(N + 15) / 16, 256, 0, stream>>>(F, WQh, WQl, WKV, ipb,
                                               Q, FkB, FvB, N);
    k_attn<<<N, 256, 0, stream>>>(coords, kidx, (const u8*)kmask,
                                  (const int*)kmask, mflag, Q, FkB, FvB,
                                  wk, wv, kpw, kpb, CTX);
    k_proj_ln_m<<<(N + 15) / 16, 256, 0, stream>>>(CTX, F, WBo, opb,
                                                   ln1g, ln1b, X1, N, 0);
    k_ff1_m<<<(N + 15) / 16, 256, 0, stream>>>(X1, WB1, b1, HID, N);
    k_ff2_ln_m<<<(N + 15) / 16, 256, 0, stream>>>(HID, X1, WB2, b2,
                                                  ln2g, ln2b, X2, N);
    k_proj_ln_m<<<(N + 15) / 16, 256, 0, stream>>>(X2, nullptr, WBw, ob,
                                                   ln3g, ln3b, (float*)d_out, N, 1);
}